// Round 6
// baseline (653.761 us; speedup 1.0000x reference)
//
#include <hip/hip_runtime.h>
#include <hip/hip_bf16.h>

using bf16 = __hip_bfloat16;
typedef short bf16x8 __attribute__((ext_vector_type(8)));
typedef float f32x4 __attribute__((ext_vector_type(4)));

__device__ inline float b2f(bf16 h) { return __bfloat162float(h); }
__device__ inline bf16 f2b(float f) { return __float2bfloat16(f); }
__device__ inline unsigned short f2bu(float f) {
    bf16 h = __float2bfloat16(f);
    unsigned short u;
    __builtin_memcpy(&u, &h, 2);
    return u;
}
__device__ inline float su2f(unsigned short u) {
    unsigned v = ((unsigned)u) << 16;
    return __uint_as_float(v);
}
// NewGELU. 0.5*x*(1+tanh(z)) == x * sigmoid(2z); computed with HW exp.
__device__ inline float gelu_new(float x) {
    float x3 = x * x * x;
    float z2 = 1.5957691216057308f * __builtin_fmaf(0.044715f, x3, x); // 2*c*(x+0.044715x^3)
    float e = __expf(-z2);   // v_exp_f32 (quarter-rate)
    return x / (1.0f + e);   // exact limits: e->inf => 0
}

// ---------------- weight pack: [O][I][3][3] f32 -> [tap][O][I] bf16 ----------
__global__ __launch_bounds__(256) void pack_w(const float* __restrict__ w,
                                              bf16* __restrict__ wpk,
                                              int CO, int CI) {
    int i = blockIdx.x * 256 + threadIdx.x;
    int total = CO * CI * 9;
    if (i < total) {
        int tap = i % 9;
        int ci = (i / 9) % CI;
        int co = i / (9 * CI);
        wpk[((size_t)tap * CO + co) * CI + ci] = f2b(w[i]);
    }
}

// ---------------- g/b transpose NCHW f32 -> NHWC f32 ----------
__global__ __launch_bounds__(256) void gtrans_k(const float* __restrict__ g,
                                                const float* __restrict__ bb,
                                                float* __restrict__ gt,
                                                float* __restrict__ bt) {
    int i = blockIdx.x * 256 + threadIdx.x;
    int sel = i >> 17;
    int o = i & 131071;
    int p = o >> 5, c = o & 31;
    int src = c * 4096 + p;
    if (sel == 0) gt[o] = g[src];
    else          bt[o] = bb[src];
}

// ---------------- LN partial reduce: grid (8, 128) ----------------
template <typename TIN>
__global__ __launch_bounds__(256) void ln_part(const void* __restrict__ xin,
                                               float2* __restrict__ spart) {
    const int tid = threadIdx.x;
    const int sample = blockIdx.y, seg = blockIdx.x;
    const size_t base = (size_t)sample * 131072 + seg * 16384;
    float sum = 0.f, ss = 0.f;
    if constexpr (sizeof(TIN) == 4) {
        const float4* p = (const float4*)((const float*)xin + base);
        for (int l = 0; l < 16; ++l) {
            float4 v = p[l * 256 + tid];
            sum += v.x + v.y + v.z + v.w;
            ss += v.x * v.x + v.y * v.y + v.z * v.z + v.w * v.w;
        }
    } else {
        const uint4* p = (const uint4*)((const bf16*)xin + base);
        for (int l = 0; l < 8; ++l) {
            uint4 u = p[l * 256 + tid];
            unsigned w[4] = {u.x, u.y, u.z, u.w};
#pragma unroll
            for (int j = 0; j < 4; ++j) {
                float lo = __uint_as_float(w[j] << 16);
                float hi = __uint_as_float(w[j] & 0xffff0000u);
                sum += lo + hi;
                ss += lo * lo + hi * hi;
            }
        }
    }
    __shared__ float rs[256], rs2[256];
    rs[tid] = sum; rs2[tid] = ss;
    __syncthreads();
    for (int off = 128; off > 0; off >>= 1) {
        if (tid < off) { rs[tid] += rs[tid + off]; rs2[tid] += rs2[tid + off]; }
        __syncthreads();
    }
    if (tid == 0) spart[sample * 8 + seg] = make_float2(rs[0], rs2[0]);
}

// ---------------- LN finalize ----------------
__global__ __launch_bounds__(128) void ln_fin(const float2* __restrict__ spart,
                                              float2* __restrict__ stats) {
    int t = threadIdx.x;
    float s = 0.f, ss = 0.f;
    for (int j = 0; j < 8; ++j) {
        float2 v = spart[t * 8 + j];
        s += v.x; ss += v.y;
    }
    float m = s / 131072.f;
    float var = ss / 131072.f - m * m;
    stats[t] = make_float2(m, rsqrtf(var + 1e-5f));
}

// ---------------- LN1 normalize + NCHW->NHWC transpose ----------------
__global__ __launch_bounds__(256) void ln1_norm_t(const float* __restrict__ x,
                                                  const float* __restrict__ g,
                                                  const float* __restrict__ bb,
                                                  const float2* __restrict__ stats,
                                                  bf16* __restrict__ out) {
    __shared__ float tile[32][129];
    const int tid = threadIdx.x;
    const int sample = blockIdx.y;
    const int p0 = blockIdx.x * 128;
    float2 st = stats[sample];
    const float m = st.x, r = st.y;
    const size_t xb = (size_t)sample * 131072;
    for (int k = 0; k < 16; ++k) {
        int idx = k * 256 + tid;
        int c = idx >> 7, p = idx & 127;
        int gi = c * 4096 + p0 + p;
        float v = x[xb + gi];
        tile[c][p] = (v - m) * r * g[gi] + bb[gi];
    }
    __syncthreads();
    for (int k = 0; k < 8; ++k) {
        int idx = k * 256 + tid;
        int p = idx >> 4, c2 = (idx & 15) * 2;
        unsigned lo = (unsigned)f2bu(tile[c2][p]);
        unsigned hi = (unsigned)f2bu(tile[c2 + 1][p]);
        *(unsigned*)&out[xb + (size_t)(p0 + p) * 32 + c2] = lo | (hi << 16);
    }
}

// ---------------- LN2 normalize, NHWC linear ----------------
__global__ __launch_bounds__(256) void ln2_norm(const bf16* __restrict__ xin,
                                                const float* __restrict__ gt,
                                                const float* __restrict__ bt,
                                                const float2* __restrict__ stats,
                                                bf16* __restrict__ out) {
    const int tid = threadIdx.x;
    const int sample = blockIdx.y;
    float2 st = stats[sample];
    const float m = st.x, r = st.y;
    int i0 = (blockIdx.x * 256 + tid) * 8;
    const size_t base = (size_t)sample * 131072 + i0;
    uint4 u = *(const uint4*)&xin[base];
    float4 g0 = *(const float4*)&gt[i0];
    float4 g1 = *(const float4*)&gt[i0 + 4];
    float4 b0 = *(const float4*)&bt[i0];
    float4 b1 = *(const float4*)&bt[i0 + 4];
    unsigned w[4] = {u.x, u.y, u.z, u.w};
    float gv[8] = {g0.x, g0.y, g0.z, g0.w, g1.x, g1.y, g1.z, g1.w};
    float bv[8] = {b0.x, b0.y, b0.z, b0.w, b1.x, b1.y, b1.z, b1.w};
    unsigned o[4];
#pragma unroll
    for (int j = 0; j < 4; ++j) {
        float lo = __uint_as_float(w[j] << 16);
        float hi = __uint_as_float(w[j] & 0xffff0000u);
        lo = (lo - m) * r * gv[2 * j] + bv[2 * j];
        hi = (hi - m) * r * gv[2 * j + 1] + bv[2 * j + 1];
        o[j] = (unsigned)f2bu(lo) | ((unsigned)f2bu(hi) << 16);
    }
    uint4 st4 = make_uint4(o[0], o[1], o[2], o[3]);
    *(uint4*)&out[base] = st4;
}

// ---------------- stride-1 conv: both operands staged in LDS (R3 version) ---
template <int CI, int CO_TOTAL, int CO_BLK, int EPI>
__global__ __launch_bounds__(256) void conv_lds(const bf16* __restrict__ in,
                                                const bf16* __restrict__ wpk,
                                                const float* __restrict__ bias,
                                                const void* __restrict__ res,
                                                void* __restrict__ out,
                                                int in_s0, int out_s0) {
    constexpr int CHUNKS = CI / 32;
    constexpr int MT = CO_BLK / 16;
    constexpr int NG = 16;

    __shared__ short s_in[6 * 66 * 32];
    __shared__ short s_w[9 * CO_BLK * 32];

    const int tid = threadIdx.x;
    const int lane = tid & 63;
    const int wv = tid >> 6;
    const int quad = lane >> 4;
    const int n16 = lane & 15;

    const int ng = blockIdx.x % NG;
    const int cg = blockIdx.x / NG;
    const int co0 = cg * CO_BLK;
    const int smp = blockIdx.y;
    const int y0 = ng * 4;

    f32x4 acc[MT][4];
#pragma unroll
    for (int mt = 0; mt < MT; ++mt)
#pragma unroll
        for (int j = 0; j < 4; ++j) acc[mt][j] = (f32x4){0.f, 0.f, 0.f, 0.f};

    const size_t in_base = (size_t)(in_s0 + smp) * 4096 * CI;

    for (int chunk = 0; chunk < CHUNKS; ++chunk) {
        const int ci0 = chunk * 32;
        __syncthreads();
        for (int i = tid; i < 6 * 66 * 4; i += 256) {
            int sub = i & 3;
            int x = (i >> 2) % 66;
            int row = i / 264;
            int y = y0 + row - 1;
            int xg = x - 1;
            uint4 u = make_uint4(0u, 0u, 0u, 0u);
            if (y >= 0 && y < 64 && xg >= 0 && xg < 64)
                u = *(const uint4*)&in[in_base + ((size_t)y * 64 + xg) * CI + ci0 + sub * 8];
            int ps = sub ^ (x & 3) ^ ((x >> 2) & 1);
            *(uint4*)&s_in[(row * 66 + x) * 32 + ps * 8] = u;
        }
        for (int i = tid; i < 9 * CO_BLK * 4; i += 256) {
            int sub = i & 3;
            int co = (i >> 2) % CO_BLK;
            int tap = i / (CO_BLK * 4);
            uint4 u = *(const uint4*)&wpk[((size_t)tap * CO_TOTAL + co0 + co) * CI + ci0 + sub * 8];
            int ps = sub ^ (co & 3) ^ ((co >> 2) & 1);
            *(uint4*)&s_w[(tap * CO_BLK + co) * 32 + ps * 8] = u;
        }
        __syncthreads();

#pragma unroll
        for (int ky = 0; ky < 3; ++ky) {
#pragma unroll
            for (int kx = 0; kx < 3; ++kx) {
                const int tap = ky * 3 + kx;
                bf16x8 bfrag[4];
#pragma unroll
                for (int j = 0; j < 4; ++j) {
                    int x = j * 16 + n16 + kx;
                    int ps = quad ^ (x & 3) ^ ((x >> 2) & 1);
                    bfrag[j] = *(const bf16x8*)&s_in[((wv + ky) * 66 + x) * 32 + ps * 8];
                }
#pragma unroll
                for (int mt = 0; mt < MT; ++mt) {
                    int mrow = mt * 16 + n16;
                    int ps = quad ^ (mrow & 3) ^ ((mrow >> 2) & 1);
                    bf16x8 afrag = *(const bf16x8*)&s_w[(tap * CO_BLK + mrow) * 32 + ps * 8];
#pragma unroll
                    for (int j = 0; j < 4; ++j)
                        acc[mt][j] = __builtin_amdgcn_mfma_f32_16x16x32_bf16(afrag, bfrag[j], acc[mt][j], 0, 0, 0);
                }
            }
        }
    }

    const int osmp = out_s0 + smp;
#pragma unroll
    for (int j = 0; j < 4; ++j) {
        int pos = (y0 + wv) * 64 + j * 16 + n16;
#pragma unroll
        for (int mt = 0; mt < MT; ++mt) {
            int coutb = co0 + mt * 16 + quad * 4;
            float b0 = 0.f, b1 = 0.f, b2 = 0.f, b3 = 0.f;
            if constexpr (EPI != 1) {
                float4 bv = *(const float4*)&bias[coutb];
                b0 = bv.x; b1 = bv.y; b2 = bv.z; b3 = bv.w;
            }
            float v0 = acc[mt][j][0] + b0;
            float v1 = acc[mt][j][1] + b1;
            float v2 = acc[mt][j][2] + b2;
            float v3 = acc[mt][j][3] + b3;
            if constexpr (EPI == 1 || EPI == 2 || EPI == 3) {
                if constexpr (EPI == 2) {
                    const float* xr = (const float*)res + (size_t)osmp * 131072 + (size_t)coutb * 4096 + pos;
                    v0 += xr[0]; v1 += xr[4096]; v2 += xr[8192]; v3 += xr[12288];
                } else if constexpr (EPI == 3) {
                    v0 = gelu_new(v0); v1 = gelu_new(v1); v2 = gelu_new(v2); v3 = gelu_new(v3);
                }
                ushort4 st;
                st.x = f2bu(v0); st.y = f2bu(v1); st.z = f2bu(v2); st.w = f2bu(v3);
                *(ushort4*)&((bf16*)out)[((size_t)osmp * 4096 + pos) * CO_TOTAL + coutb] = st;
            } else {
                ushort4 rv = *(const ushort4*)&((const bf16*)res)[((size_t)osmp * 4096 + pos) * 32 + coutb];
                v0 += su2f(rv.x); v1 += su2f(rv.y); v2 += su2f(rv.z); v3 += su2f(rv.w);
                float* op = (float*)out + (size_t)osmp * 131072 + (size_t)coutb * 4096 + pos;
                op[0] = v0; op[4096] = v1; op[8192] = v2; op[12288] = v3;
            }
        }
    }
}

// ---------------- stride-1 conv: NO LDS, direct-from-cache operands ---------
// Mixer convs only: input is L2/L3-resident (xn2 = 32 MB in L3; Hb per-block
// slice = 96 KB with 9x tap reuse in L2; weights 72 KB L2-resident). No
// barriers, no staging => no chunk-boundary latency exposure; occupancy is
// VGPR-bound instead of LDS-bound. bfrag loads are 64-lane coalesced.
template <int CI, int CO_TOTAL, int CO_BLK, int EPI>
__global__ __launch_bounds__(256) void conv_direct(const bf16* __restrict__ in,
                                                   const bf16* __restrict__ wpk,
                                                   const float* __restrict__ bias,
                                                   const void* __restrict__ res,
                                                   void* __restrict__ out,
                                                   int in_s0, int out_s0) {
    constexpr int CHUNKS = CI / 32;
    constexpr int MT = CO_BLK / 16;
    constexpr int NG = 16;

    const int tid = threadIdx.x;
    const int lane = tid & 63;
    const int wv = tid >> 6;
    const int quad = lane >> 4;
    const int n16 = lane & 15;

    const int ng = blockIdx.x % NG;
    const int cg = blockIdx.x / NG;
    const int co0 = cg * CO_BLK;
    const int smp = blockIdx.y;
    const int y0 = ng * 4;

    f32x4 acc[MT][4];
#pragma unroll
    for (int mt = 0; mt < MT; ++mt)
#pragma unroll
        for (int j = 0; j < 4; ++j) acc[mt][j] = (f32x4){0.f, 0.f, 0.f, 0.f};

    const size_t in_base = (size_t)(in_s0 + smp) * 4096 * CI;
    const int yrow = y0 + wv;

    for (int chunk = 0; chunk < CHUNKS; ++chunk) {
        const int ci0 = chunk * 32;
#pragma unroll
        for (int ky = 0; ky < 3; ++ky) {
            const int yi = yrow + ky - 1;
            const bool yok = (yi >= 0) && (yi < 64);
#pragma unroll
            for (int kx = 0; kx < 3; ++kx) {
                const int tap = ky * 3 + kx;
                bf16x8 bfrag[4];
#pragma unroll
                for (int j = 0; j < 4; ++j) {
                    int xi = j * 16 + n16 + kx - 1;
                    bool ok = yok && (xi >= 0) && (xi < 64);
                    uint4 u = make_uint4(0u, 0u, 0u, 0u);
                    if (ok)
                        u = *(const uint4*)&in[in_base + ((size_t)yi * 64 + xi) * CI + ci0 + quad * 8];
                    __builtin_memcpy(&bfrag[j], &u, 16);
                }
#pragma unroll
                for (int mt = 0; mt < MT; ++mt) {
                    bf16x8 afrag;
                    uint4 w = *(const uint4*)&wpk[((size_t)tap * CO_TOTAL + co0 + mt * 16 + n16) * CI + ci0 + quad * 8];
                    __builtin_memcpy(&afrag, &w, 16);
#pragma unroll
                    for (int j = 0; j < 4; ++j)
                        acc[mt][j] = __builtin_amdgcn_mfma_f32_16x16x32_bf16(afrag, bfrag[j], acc[mt][j], 0, 0, 0);
                }
            }
        }
    }

    const int osmp = out_s0 + smp;
#pragma unroll
    for (int j = 0; j < 4; ++j) {
        int pos = yrow * 64 + j * 16 + n16;
#pragma unroll
        for (int mt = 0; mt < MT; ++mt) {
            int coutb = co0 + mt * 16 + quad * 4;
            float b0 = 0.f, b1 = 0.f, b2 = 0.f, b3 = 0.f;
            if constexpr (EPI != 1) {
                float4 bv = *(const float4*)&bias[coutb];
                b0 = bv.x; b1 = bv.y; b2 = bv.z; b3 = bv.w;
            }
            float v0 = acc[mt][j][0] + b0;
            float v1 = acc[mt][j][1] + b1;
            float v2 = acc[mt][j][2] + b2;
            float v3 = acc[mt][j][3] + b3;
            if constexpr (EPI == 1 || EPI == 2 || EPI == 3) {
                if constexpr (EPI == 2) {
                    const float* xr = (const float*)res + (size_t)osmp * 131072 + (size_t)coutb * 4096 + pos;
                    v0 += xr[0]; v1 += xr[4096]; v2 += xr[8192]; v3 += xr[12288];
                } else if constexpr (EPI == 3) {
                    v0 = gelu_new(v0); v1 = gelu_new(v1); v2 = gelu_new(v2); v3 = gelu_new(v3);
                }
                ushort4 st;
                st.x = f2bu(v0); st.y = f2bu(v1); st.z = f2bu(v2); st.w = f2bu(v3);
                *(ushort4*)&((bf16*)out)[((size_t)osmp * 4096 + pos) * CO_TOTAL + coutb] = st;
            } else {
                ushort4 rv = *(const ushort4*)&((const bf16*)res)[((size_t)osmp * 4096 + pos) * 32 + coutb];
                v0 += su2f(rv.x); v1 += su2f(rv.y); v2 += su2f(rv.z); v3 += su2f(rv.w);
                float* op = (float*)out + (size_t)osmp * 131072 + (size_t)coutb * 4096 + pos;
                op[0] = v0; op[4096] = v1; op[8192] = v2; op[12288] = v3;
            }
        }
    }
}

// ---------------- stride-2 conv (k,q) ----------------
template <int CI, int CI_BLK, int CO_TOTAL, int CO_BLK, int S, int EPI>
__global__ __launch_bounds__(256) void conv_mfma(const bf16* __restrict__ in,
                                                 const bf16* __restrict__ wpk,
                                                 const float* __restrict__ bias,
                                                 const void* __restrict__ res,
                                                 void* __restrict__ out,
                                                 int in_s0, int out_s0) {
    constexpr int WO = 64 / S;
    constexpr int HO = 64 / S;
    constexpr int NG = (HO * WO) / 256;
    constexpr int TPR = WO / 16;
    constexpr int MT = CO_BLK / 16;
    constexpr int PHASES = CI / CI_BLK;
    constexpr int KC = CI_BLK / 32;
    constexpr int PAD = CI_BLK + 8;

    __shared__ short s_w[9 * CO_BLK * PAD];

    const int tid = threadIdx.x;
    const int lane = tid & 63;
    const int wv = tid >> 6;
    const int quad = lane >> 4;
    const int n16 = lane & 15;

    const int ng = blockIdx.x % NG;
    const int cg = blockIdx.x / NG;
    const int co0 = cg * CO_BLK;
    const int smp = blockIdx.y;

    f32x4 acc[MT][4];
#pragma unroll
    for (int mt = 0; mt < MT; ++mt)
#pragma unroll
        for (int j = 0; j < 4; ++j) acc[mt][j] = (f32x4){0.f, 0.f, 0.f, 0.f};

    const size_t in_base = (size_t)(in_s0 + smp) * 4096 * CI;

    for (int phase = 0; phase < PHASES; ++phase) {
        const int ci0 = phase * CI_BLK;
        __syncthreads();
        for (int idx = tid; idx < 9 * CO_BLK * CI_BLK / 4; idx += 256) {
            int e = idx * 4;
            int tap = e / (CO_BLK * CI_BLK);
            int rem = e - tap * (CO_BLK * CI_BLK);
            int col = rem / CI_BLK;
            int k = rem - col * CI_BLK;
            const ushort4 src = *(const ushort4*)&wpk[((size_t)tap * CO_TOTAL + co0 + col) * CI + ci0 + k];
            *(ushort4*)&s_w[(tap * CO_BLK + col) * PAD + k] = src;
        }
        __syncthreads();

#pragma unroll
        for (int ky = 0; ky < 3; ++ky) {
#pragma unroll
            for (int kx = 0; kx < 3; ++kx) {
                const int tap = ky * 3 + kx;
                bf16x8 bfrag[KC][4];
#pragma unroll
                for (int kc = 0; kc < KC; ++kc) {
#pragma unroll
                    for (int j = 0; j < 4; ++j) {
                        int tile = ng * 16 + wv * 4 + j;
                        int yo = tile / TPR;
                        int xo = (tile % TPR) * 16;
                        int xi = (xo + n16) * S + kx - 1;
                        int yi = yo * S + ky - 1;
                        bool valid = (xi >= 0) && (xi < 64) && (yi >= 0) && (yi < 64);
                        uint4 u;
                        if (valid)
                            u = *(const uint4*)&in[in_base + ((size_t)yi * 64 + xi) * CI + ci0 + kc * 32 + quad * 8];
                        else
                            u = make_uint4(0u, 0u, 0u, 0u);
                        __builtin_memcpy(&bfrag[kc][j], &u, 16);
                    }
                }
#pragma unroll
                for (int kc = 0; kc < KC; ++kc) {
#pragma unroll
                    for (int mt = 0; mt < MT; ++mt) {
                        bf16x8 afrag = *(const bf16x8*)&s_w[(tap * CO_BLK + mt * 16 + n16) * PAD + kc * 32 + quad * 8];
#pragma unroll
                        for (int j = 0; j < 4; ++j)
                            acc[mt][j] = __builtin_amdgcn_mfma_f32_16x16x32_bf16(afrag, bfrag[kc][j], acc[mt][j], 0, 0, 0);
                    }
                }
            }
        }
    }

    const int osmp = out_s0 + smp;
#pragma unroll
    for (int j = 0; j < 4; ++j) {
        int tile = ng * 16 + wv * 4 + j;
        int yo = tile / TPR;
        int xo = (tile % TPR) * 16;
        int pos = yo * WO + xo + n16;
#pragma unroll
        for (int mt = 0; mt < MT; ++mt) {
            int coutb = co0 + mt * 16 + quad * 4;
            ushort4 st;
            st.x = f2bu(acc[mt][j][0]); st.y = f2bu(acc[mt][j][1]);
            st.z = f2bu(acc[mt][j][2]); st.w = f2bu(acc[mt][j][3]);
            *(ushort4*)&((bf16*)out)[((size_t)osmp * HO * WO + pos) * CO_TOTAL + coutb] = st;
        }
    }
}

// ---------------- attention scores + softmax : fused MFMA ----------------
__global__ __launch_bounds__(256) void attn_scores_mfma(const bf16* __restrict__ Q,
                                                        const bf16* __restrict__ K,
                                                        bf16* __restrict__ att) {
    __shared__ float red[4][32][33];
    __shared__ float sc[32][33];
    const int tid = threadIdx.x;
    const int lane = tid & 63;
    const int wv = tid >> 6;
    const int quad = lane >> 4;
    const int n16 = lane & 15;
    const int h = blockIdx.x & 7;
    const int b = blockIdx.x >> 3;
    const size_t base = (size_t)b * 32 * 32768 + (size_t)h * 4;

    f32x4 acc[2][2];
#pragma unroll
    for (int mt = 0; mt < 2; ++mt)
#pragma unroll
        for (int nt = 0; nt < 2; ++nt) acc[mt][nt] = (f32x4){0.f, 0.f, 0.f, 0.f};

    for (int kc = 0; kc < 32; ++kc) {
        const int p0 = wv * 256 + kc * 8 + quad * 2;
        bf16x8 afrag[2], bfrag[2];
#pragma unroll
        for (int mt = 0; mt < 2; ++mt) {
            const bf16* qp = &Q[base + (size_t)(mt * 16 + n16) * 32768 + (size_t)p0 * 32];
            uint2 lo = *(const uint2*)qp;
            uint2 hi = *(const uint2*)(qp + 32);
            uint4 u = make_uint4(lo.x, lo.y, hi.x, hi.y);
            __builtin_memcpy(&afrag[mt], &u, 16);
        }
#pragma unroll
        for (int nt = 0; nt < 2; ++nt) {
            const bf16* kp = &K[base + (size_t)(nt * 16 + n16) * 32768 + (size_t)p0 * 32];
            uint2 lo = *(const uint2*)kp;
            uint2 hi = *(const uint2*)(kp + 32);
            uint4 u = make_uint4(lo.x, lo.y, hi.x, hi.y);
            __builtin_memcpy(&bfrag[nt], &u, 16);
        }
#pragma unroll
        for (int mt = 0; mt < 2; ++mt)
#pragma unroll
            for (int nt = 0; nt < 2; ++nt)
                acc[mt][nt] = __builtin_amdgcn_mfma_f32_16x16x32_bf16(afrag[mt], bfrag[nt], acc[mt][nt], 0, 0, 0);
    }
#pragma unroll
    for (int mt = 0; mt < 2; ++mt)
#pragma unroll
        for (int nt = 0; nt < 2; ++nt)
#pragma unroll
            for (int r = 0; r < 4; ++r)
                red[wv][mt * 16 + quad * 4 + r][nt * 16 + n16] = acc[mt][nt][r];
    __syncthreads();
    for (int i = tid; i < 1024; i += 256) {
        int t = i >> 5, s = i & 31;
        sc[t][s] = (red[0][t][s] + red[1][t][s] + red[2][t][s] + red[3][t][s]) * (1.0f / 64.0f);
    }
    __syncthreads();
    if (tid < 32) {
        float mx = -1e30f;
        for (int s2 = 0; s2 < 32; ++s2) mx = fmaxf(mx, sc[tid][s2]);
        float sum = 0.f;
        for (int s2 = 0; s2 < 32; ++s2) sum += expf(sc[tid][s2] - mx);
        float inv = 1.f / sum;
        bf16* arow = &att[((size_t)blockIdx.x * 32 + tid) * 32];
        for (int s2 = 0; s2 < 32; ++s2) arow[s2] = f2b(expf(sc[tid][s2] - mx) * inv);
    }
}

// ---------------- y = att @ v : MFMA with fused in-LDS V transpose ----------
__global__ __launch_bounds__(256) void attn_apply_mfma(const bf16* __restrict__ att,
                                                       const bf16* __restrict__ V,
                                                       bf16* __restrict__ Y) {
    __shared__ short vlds[512 * 40];
    __shared__ short ylds[32 * 512];
    const int tid = threadIdx.x;
    const int lane = tid & 63;
    const int wv = tid >> 6;
    const int quad = lane >> 4;
    const int n16 = lane & 15;
    const int pb = blockIdx.x;
    const int b = blockIdx.y;

    for (int l = 0; l < 8; ++l) {
        int u = l * 256 + tid;
        int s = u >> 6;
        int col8 = (u & 63) * 8;
        uint4 v = *(const uint4*)&V[(((size_t)(b * 32 + s) * 4096 + pb * 16) * 32) + col8];
        unsigned short us[8];
        __builtin_memcpy(us, &v, 16);
#pragma unroll
        for (int j = 0; j < 8; ++j) {
            int idx = col8 + j;
            int p = idx >> 5, c = idx & 31;
            int row = ((c >> 2) * 16 + p) * 4 + (c & 3);
            vlds[row * 40 + s] = (short)us[j];
        }
    }
    __syncthreads();

    const int e = wv * 16 + n16;
    const int p = e >> 2, cl = e & 3;
    for (int h = 0; h < 8; ++h) {
        bf16x8 bfrag = *(const bf16x8*)&vlds[(h * 64 + e) * 40 + quad * 8];
        const int c = h * 4 + cl;
#pragma unroll
        for (int mt = 0; mt < 2; ++mt) {
            bf16x8 afrag = *(const bf16x8*)&att[((size_t)(b * 8 + h) * 32 + mt * 16 + n16) * 32 + quad * 8];
            f32x4 d = __builtin_amdgcn_mfma_f32_16x16x32_bf16(afrag, bfrag,
                                                              (f32x4){0.f, 0.f, 0.f, 0.f}, 0, 0, 0);
#pragma unroll
            for (int r = 0; r < 4; ++r) {
                int t = mt * 16 + quad * 4 + r;
                ylds[t * 512 + p * 32 + c] = (short)f2bu(d[r]);
            }
        }
    }
    __syncthreads();

    for (int l = 0; l < 8; ++l) {
        int u = l * 256 + tid;
        int t = u >> 6;
        int col8 = (u & 63) * 8;
        *(uint4*)&Y[(((size_t)(b * 32 + t) * 4096 + pb * 16) * 32) + col8] =
            *(const uint4*)&ylds[t * 512 + col8];
    }
}

extern "C" void kernel_launch(void* const* d_in, const int* in_sizes, int n_in,
                              void* d_out, int out_size, void* d_ws, size_t ws_size,
                              hipStream_t stream) {
    const float* x   = (const float*)d_in[0];
    const float* n1g = (const float*)d_in[1];
    const float* n1b = (const float*)d_in[2];
    const float* n2g = (const float*)d_in[3];
    const float* n2b = (const float*)d_in[4];
    const float* Wk  = (const float*)d_in[5];
    const float* Wq  = (const float*)d_in[6];
    const float* Wv  = (const float*)d_in[7];
    const float* Wo  = (const float*)d_in[8];
    const float* bo  = (const float*)d_in[9];
    const float* Wm1 = (const float*)d_in[10];
    const float* bm1 = (const float*)d_in[11];
    const float* Wm2 = (const float*)d_in[12];
    const float* bm2 = (const float*)d_in[13];

    char* ws = (char*)d_ws;
    const size_t A_OFF = 0;
    const size_t B_OFF = 33554432;
    const size_t D_OFF = 67108864;
    const size_t E_OFF = 67239936;
    const size_t F_OFF = 67461120;
    const size_t C_OFF = 68519936;
    const size_t Q_OFF = C_OFF + 8388608;

    bf16*  xn   = (bf16*)(ws + A_OFF);
    bf16*  Yb   = (bf16*)(ws + A_OFF);
    bf16*  xn2  = (bf16*)(ws + A_OFF);
    bf16*  Vb   = (bf16*)(ws + B_OFF);
    bf16*  X1   = (bf16*)(ws + B_OFF);
    bf16*  attbf = (bf16*)(ws + D_OFF);
    bf16*  wpk_k  = (bf16*)(ws + E_OFF);
    bf16*  wpk_q  = (bf16*)(ws + E_OFF + 18432);
    bf16*  wpk_v  = (bf16*)(ws + E_OFF + 36864);
    bf16*  wpk_o  = (bf16*)(ws + E_OFF + 55296);
    bf16*  wpk_m1 = (bf16*)(ws + E_OFF + 73728);
    bf16*  wpk_m2 = (bf16*)(ws + E_OFF + 147456);
    float* g2t  = (float*)(ws + F_OFF);
    float* b2t  = (float*)(ws + F_OFF + 524288);
    float2* spart = (float2*)(ws + F_OFF + 1048576);
    float2* stats = (float2*)(ws + F_OFF + 1056768);
    bf16*  Kb   = (bf16*)(ws + C_OFF);
    bf16*  Qb   = (bf16*)(ws + Q_OFF);
    bf16*  Hb   = (bf16*)(ws + C_OFF);

    const size_t HB_PER_SAMPLE = 1048576;
    int chunk = 128;
    if (ws_size < C_OFF + 128 * HB_PER_SAMPLE) {
        size_t avail = (ws_size > C_OFF) ? (ws_size - C_OFF) : HB_PER_SAMPLE;
        chunk = (int)(avail / HB_PER_SAMPLE);
        if (chunk < 1) chunk = 1;
        if (chunk > 128) chunk = 128;
    }

    // 0. pack weights; transpose LN2 gamma/beta
    pack_w<<<36, 256, 0, stream>>>(Wk, wpk_k, 32, 32);
    pack_w<<<36, 256, 0, stream>>>(Wq, wpk_q, 32, 32);
    pack_w<<<36, 256, 0, stream>>>(Wv, wpk_v, 32, 32);
    pack_w<<<36, 256, 0, stream>>>(Wo, wpk_o, 32, 32);
    pack_w<<<144, 256, 0, stream>>>(Wm1, wpk_m1, 128, 32);
    pack_w<<<144, 256, 0, stream>>>(Wm2, wpk_m2, 32, 128);
    gtrans_k<<<1024, 256, 0, stream>>>(n2g, n2b, g2t, b2t);

    // 1. LN1: x (NCHW f32) -> xn (NHWC bf16)
    ln_part<float><<<dim3(8, 128), 256, 0, stream>>>(x, spart);
    ln_fin<<<1, 128, 0, stream>>>(spart, stats);
    ln1_norm_t<<<dim3(32, 128), 256, 0, stream>>>(x, n1g, n1b, stats, xn);
    // 2-4. k,q (stride 2), v (stride 1 LDS) — unchanged controls
    conv_mfma<32, 32, 32, 32, 2, 1><<<dim3(4, 128), 256, 0, stream>>>(xn, wpk_k, nullptr, nullptr, Kb, 0, 0);
    conv_mfma<32, 32, 32, 32, 2, 1><<<dim3(4, 128), 256, 0, stream>>>(xn, wpk_q, nullptr, nullptr, Qb, 0, 0);
    conv_lds<32, 32, 32, 1><<<dim3(16, 128), 256, 0, stream>>>(xn, wpk_v, nullptr, nullptr, Vb, 0, 0);
    // 5. attention scores + softmax (fused MFMA)
    attn_scores_mfma<<<32, 256, 0, stream>>>(Qb, Kb, attbf);
    // 6. y = att @ v
    attn_apply_mfma<<<dim3(256, 4), 256, 0, stream>>>(attbf, Vb, Yb);
    // 7. Wo conv + bias + residual x -> X1 — unchanged control
    conv_lds<32, 32, 32, 2><<<dim3(16, 128), 256, 0, stream>>>(Yb, wpk_o, bo, x, X1, 0, 0);
    // 8. LN2
    ln_part<bf16><<<dim3(8, 128), 256, 0, stream>>>(X1, spart);
    ln_fin<<<1, 128, 0, stream>>>(spart, stats);
    ln2_norm<<<dim3(64, 128), 256, 0, stream>>>(X1, g2t, b2t, stats, xn2);
    // 9-10. mixer: barrier-free direct-from-cache convs (experiment)
    for (int s0 = 0; s0 < 128; s0 += chunk) {
        int n = (128 - s0 < chunk) ? (128 - s0) : chunk;
        conv_direct<32, 128, 64, 3><<<dim3(32, n), 256, 0, stream>>>(xn2, wpk_m1, bm1, nullptr, Hb, s0, 0);
        conv_direct<128, 32, 32, 4><<<dim3(16, n), 256, 0, stream>>>(Hb, wpk_m2, bm2, X1, (float*)d_out, 0, s0);
    }
}

// Round 7
// 551.927 us; speedup vs baseline: 1.1845x; 1.1845x over previous
//
#include <hip/hip_runtime.h>
#include <hip/hip_bf16.h>

using bf16 = __hip_bfloat16;
typedef short bf16x8 __attribute__((ext_vector_type(8)));
typedef float f32x4 __attribute__((ext_vector_type(4)));

__device__ inline float b2f(bf16 h) { return __bfloat162float(h); }
__device__ inline bf16 f2b(float f) { return __float2bfloat16(f); }
__device__ inline unsigned short f2bu(float f) {
    bf16 h = __float2bfloat16(f);
    unsigned short u;
    __builtin_memcpy(&u, &h, 2);
    return u;
}
__device__ inline float su2f(unsigned short u) {
    unsigned v = ((unsigned)u) << 16;
    return __uint_as_float(v);
}
// NewGELU. 0.5*x*(1+tanh(z)) == x * sigmoid(2z); computed with HW exp.
__device__ inline float gelu_new(float x) {
    float x3 = x * x * x;
    float z2 = 1.5957691216057308f * __builtin_fmaf(0.044715f, x3, x); // 2*c*(x+0.044715x^3)
    float e = __expf(-z2);   // v_exp_f32 (quarter-rate)
    return x / (1.0f + e);   // exact limits: e->inf => 0
}

// ---------------- weight pack: [O][I][3][3] f32 -> [tap][CO_TOTAL][CI] bf16 --
// co_off places this source's output channels inside a wider packed tensor.
__global__ __launch_bounds__(256) void pack_w(const float* __restrict__ w,
                                              bf16* __restrict__ wpk,
                                              int CO, int CI, int CO_TOTAL, int co_off) {
    int i = blockIdx.x * 256 + threadIdx.x;
    int total = CO * CI * 9;
    if (i < total) {
        int tap = i % 9;
        int ci = (i / 9) % CI;
        int co = i / (9 * CI);
        wpk[((size_t)tap * CO_TOTAL + co_off + co) * CI + ci] = f2b(w[i]);
    }
}

// ---------------- g/b transpose NCHW f32 -> NHWC f32 ----------
__global__ __launch_bounds__(256) void gtrans_k(const float* __restrict__ g,
                                                const float* __restrict__ bb,
                                                float* __restrict__ gt,
                                                float* __restrict__ bt) {
    int i = blockIdx.x * 256 + threadIdx.x;
    int sel = i >> 17;
    int o = i & 131071;
    int p = o >> 5, c = o & 31;
    int src = c * 4096 + p;
    if (sel == 0) gt[o] = g[src];
    else          bt[o] = bb[src];
}

// ---------------- LN partial reduce: grid (8, 128) ----------------
template <typename TIN>
__global__ __launch_bounds__(256) void ln_part(const void* __restrict__ xin,
                                               float2* __restrict__ spart) {
    const int tid = threadIdx.x;
    const int sample = blockIdx.y, seg = blockIdx.x;
    const size_t base = (size_t)sample * 131072 + seg * 16384;
    float sum = 0.f, ss = 0.f;
    if constexpr (sizeof(TIN) == 4) {
        const float4* p = (const float4*)((const float*)xin + base);
        for (int l = 0; l < 16; ++l) {
            float4 v = p[l * 256 + tid];
            sum += v.x + v.y + v.z + v.w;
            ss += v.x * v.x + v.y * v.y + v.z * v.z + v.w * v.w;
        }
    } else {
        const uint4* p = (const uint4*)((const bf16*)xin + base);
        for (int l = 0; l < 8; ++l) {
            uint4 u = p[l * 256 + tid];
            unsigned w[4] = {u.x, u.y, u.z, u.w};
#pragma unroll
            for (int j = 0; j < 4; ++j) {
                float lo = __uint_as_float(w[j] << 16);
                float hi = __uint_as_float(w[j] & 0xffff0000u);
                sum += lo + hi;
                ss += lo * lo + hi * hi;
            }
        }
    }
    __shared__ float rs[256], rs2[256];
    rs[tid] = sum; rs2[tid] = ss;
    __syncthreads();
    for (int off = 128; off > 0; off >>= 1) {
        if (tid < off) { rs[tid] += rs[tid + off]; rs2[tid] += rs2[tid + off]; }
        __syncthreads();
    }
    if (tid == 0) spart[sample * 8 + seg] = make_float2(rs[0], rs2[0]);
}

// ---------------- LN finalize ----------------
__global__ __launch_bounds__(128) void ln_fin(const float2* __restrict__ spart,
                                              float2* __restrict__ stats) {
    int t = threadIdx.x;
    float s = 0.f, ss = 0.f;
    for (int j = 0; j < 8; ++j) {
        float2 v = spart[t * 8 + j];
        s += v.x; ss += v.y;
    }
    float m = s / 131072.f;
    float var = ss / 131072.f - m * m;
    stats[t] = make_float2(m, rsqrtf(var + 1e-5f));
}

// ---------------- LN1 normalize + NCHW->NHWC transpose ----------------
__global__ __launch_bounds__(256) void ln1_norm_t(const float* __restrict__ x,
                                                  const float* __restrict__ g,
                                                  const float* __restrict__ bb,
                                                  const float2* __restrict__ stats,
                                                  bf16* __restrict__ out) {
    __shared__ float tile[32][129];
    const int tid = threadIdx.x;
    const int sample = blockIdx.y;
    const int p0 = blockIdx.x * 128;
    float2 st = stats[sample];
    const float m = st.x, r = st.y;
    const size_t xb = (size_t)sample * 131072;
    for (int k = 0; k < 16; ++k) {
        int idx = k * 256 + tid;
        int c = idx >> 7, p = idx & 127;
        int gi = c * 4096 + p0 + p;
        float v = x[xb + gi];
        tile[c][p] = (v - m) * r * g[gi] + bb[gi];
    }
    __syncthreads();
    for (int k = 0; k < 8; ++k) {
        int idx = k * 256 + tid;
        int p = idx >> 4, c2 = (idx & 15) * 2;
        unsigned lo = (unsigned)f2bu(tile[c2][p]);
        unsigned hi = (unsigned)f2bu(tile[c2 + 1][p]);
        *(unsigned*)&out[xb + (size_t)(p0 + p) * 32 + c2] = lo | (hi << 16);
    }
}

// ---------------- LN2 normalize, NHWC linear ----------------
__global__ __launch_bounds__(256) void ln2_norm(const bf16* __restrict__ xin,
                                                const float* __restrict__ gt,
                                                const float* __restrict__ bt,
                                                const float2* __restrict__ stats,
                                                bf16* __restrict__ out) {
    const int tid = threadIdx.x;
    const int sample = blockIdx.y;
    float2 st = stats[sample];
    const float m = st.x, r = st.y;
    int i0 = (blockIdx.x * 256 + tid) * 8;
    const size_t base = (size_t)sample * 131072 + i0;
    uint4 u = *(const uint4*)&xin[base];
    float4 g0 = *(const float4*)&gt[i0];
    float4 g1 = *(const float4*)&gt[i0 + 4];
    float4 b0 = *(const float4*)&bt[i0];
    float4 b1 = *(const float4*)&bt[i0 + 4];
    unsigned w[4] = {u.x, u.y, u.z, u.w};
    float gv[8] = {g0.x, g0.y, g0.z, g0.w, g1.x, g1.y, g1.z, g1.w};
    float bv[8] = {b0.x, b0.y, b0.z, b0.w, b1.x, b1.y, b1.z, b1.w};
    unsigned o[4];
#pragma unroll
    for (int j = 0; j < 4; ++j) {
        float lo = __uint_as_float(w[j] << 16);
        float hi = __uint_as_float(w[j] & 0xffff0000u);
        lo = (lo - m) * r * gv[2 * j] + bv[2 * j];
        hi = (hi - m) * r * gv[2 * j + 1] + bv[2 * j + 1];
        o[j] = (unsigned)f2bu(lo) | ((unsigned)f2bu(hi) << 16);
    }
    uint4 st4 = make_uint4(o[0], o[1], o[2], o[3]);
    *(uint4*)&out[base] = st4;
}

// ---------------- stride-1 conv: both operands staged in LDS (R3 version) ---
template <int CI, int CO_TOTAL, int CO_BLK, int EPI>
__global__ __launch_bounds__(256) void conv_lds(const bf16* __restrict__ in,
                                                const bf16* __restrict__ wpk,
                                                const float* __restrict__ bias,
                                                const void* __restrict__ res,
                                                void* __restrict__ out,
                                                int in_s0, int out_s0) {
    constexpr int CHUNKS = CI / 32;
    constexpr int MT = CO_BLK / 16;
    constexpr int NG = 16;

    __shared__ short s_in[6 * 66 * 32];
    __shared__ short s_w[9 * CO_BLK * 32];

    const int tid = threadIdx.x;
    const int lane = tid & 63;
    const int wv = tid >> 6;
    const int quad = lane >> 4;
    const int n16 = lane & 15;

    const int ng = blockIdx.x % NG;
    const int cg = blockIdx.x / NG;
    const int co0 = cg * CO_BLK;
    const int smp = blockIdx.y;
    const int y0 = ng * 4;

    f32x4 acc[MT][4];
#pragma unroll
    for (int mt = 0; mt < MT; ++mt)
#pragma unroll
        for (int j = 0; j < 4; ++j) acc[mt][j] = (f32x4){0.f, 0.f, 0.f, 0.f};

    const size_t in_base = (size_t)(in_s0 + smp) * 4096 * CI;

    for (int chunk = 0; chunk < CHUNKS; ++chunk) {
        const int ci0 = chunk * 32;
        __syncthreads();
        for (int i = tid; i < 6 * 66 * 4; i += 256) {
            int sub = i & 3;
            int x = (i >> 2) % 66;
            int row = i / 264;
            int y = y0 + row - 1;
            int xg = x - 1;
            uint4 u = make_uint4(0u, 0u, 0u, 0u);
            if (y >= 0 && y < 64 && xg >= 0 && xg < 64)
                u = *(const uint4*)&in[in_base + ((size_t)y * 64 + xg) * CI + ci0 + sub * 8];
            int ps = sub ^ (x & 3) ^ ((x >> 2) & 1);
            *(uint4*)&s_in[(row * 66 + x) * 32 + ps * 8] = u;
        }
        for (int i = tid; i < 9 * CO_BLK * 4; i += 256) {
            int sub = i & 3;
            int co = (i >> 2) % CO_BLK;
            int tap = i / (CO_BLK * 4);
            uint4 u = *(const uint4*)&wpk[((size_t)tap * CO_TOTAL + co0 + co) * CI + ci0 + sub * 8];
            int ps = sub ^ (co & 3) ^ ((co >> 2) & 1);
            *(uint4*)&s_w[(tap * CO_BLK + co) * 32 + ps * 8] = u;
        }
        __syncthreads();

#pragma unroll
        for (int ky = 0; ky < 3; ++ky) {
#pragma unroll
            for (int kx = 0; kx < 3; ++kx) {
                const int tap = ky * 3 + kx;
                bf16x8 bfrag[4];
#pragma unroll
                for (int j = 0; j < 4; ++j) {
                    int x = j * 16 + n16 + kx;
                    int ps = quad ^ (x & 3) ^ ((x >> 2) & 1);
                    bfrag[j] = *(const bf16x8*)&s_in[((wv + ky) * 66 + x) * 32 + ps * 8];
                }
#pragma unroll
                for (int mt = 0; mt < MT; ++mt) {
                    int mrow = mt * 16 + n16;
                    int ps = quad ^ (mrow & 3) ^ ((mrow >> 2) & 1);
                    bf16x8 afrag = *(const bf16x8*)&s_w[(tap * CO_BLK + mrow) * 32 + ps * 8];
#pragma unroll
                    for (int j = 0; j < 4; ++j)
                        acc[mt][j] = __builtin_amdgcn_mfma_f32_16x16x32_bf16(afrag, bfrag[j], acc[mt][j], 0, 0, 0);
                }
            }
        }
    }

    const int osmp = out_s0 + smp;
#pragma unroll
    for (int j = 0; j < 4; ++j) {
        int pos = (y0 + wv) * 64 + j * 16 + n16;
#pragma unroll
        for (int mt = 0; mt < MT; ++mt) {
            int coutb = co0 + mt * 16 + quad * 4;
            float b0 = 0.f, b1 = 0.f, b2 = 0.f, b3 = 0.f;
            if constexpr (EPI != 1) {
                float4 bv = *(const float4*)&bias[coutb];
                b0 = bv.x; b1 = bv.y; b2 = bv.z; b3 = bv.w;
            }
            float v0 = acc[mt][j][0] + b0;
            float v1 = acc[mt][j][1] + b1;
            float v2 = acc[mt][j][2] + b2;
            float v3 = acc[mt][j][3] + b3;
            if constexpr (EPI == 1 || EPI == 2 || EPI == 3) {
                if constexpr (EPI == 2) {
                    const float* xr = (const float*)res + (size_t)osmp * 131072 + (size_t)coutb * 4096 + pos;
                    v0 += xr[0]; v1 += xr[4096]; v2 += xr[8192]; v3 += xr[12288];
                } else if constexpr (EPI == 3) {
                    v0 = gelu_new(v0); v1 = gelu_new(v1); v2 = gelu_new(v2); v3 = gelu_new(v3);
                }
                ushort4 st;
                st.x = f2bu(v0); st.y = f2bu(v1); st.z = f2bu(v2); st.w = f2bu(v3);
                *(ushort4*)&((bf16*)out)[((size_t)osmp * 4096 + pos) * CO_TOTAL + coutb] = st;
            } else {
                ushort4 rv = *(const ushort4*)&((const bf16*)res)[((size_t)osmp * 4096 + pos) * 32 + coutb];
                v0 += su2f(rv.x); v1 += su2f(rv.y); v2 += su2f(rv.z); v3 += su2f(rv.w);
                float* op = (float*)out + (size_t)osmp * 131072 + (size_t)coutb * 4096 + pos;
                op[0] = v0; op[4096] = v1; op[8192] = v2; op[12288] = v3;
            }
        }
    }
}

// ---------------- stride-2 conv (k,q merged: CO_TOTAL=64) ----------------
template <int CI, int CI_BLK, int CO_TOTAL, int CO_BLK, int S, int EPI>
__global__ __launch_bounds__(256) void conv_mfma(const bf16* __restrict__ in,
                                                 const bf16* __restrict__ wpk,
                                                 const float* __restrict__ bias,
                                                 const void* __restrict__ res,
                                                 void* __restrict__ out,
                                                 int in_s0, int out_s0) {
    constexpr int WO = 64 / S;
    constexpr int HO = 64 / S;
    constexpr int NG = (HO * WO) / 256;
    constexpr int TPR = WO / 16;
    constexpr int MT = CO_BLK / 16;
    constexpr int PHASES = CI / CI_BLK;
    constexpr int KC = CI_BLK / 32;
    constexpr int PAD = CI_BLK + 8;

    __shared__ short s_w[9 * CO_BLK * PAD];

    const int tid = threadIdx.x;
    const int lane = tid & 63;
    const int wv = tid >> 6;
    const int quad = lane >> 4;
    const int n16 = lane & 15;

    const int ng = blockIdx.x % NG;
    const int cg = blockIdx.x / NG;
    const int co0 = cg * CO_BLK;
    const int smp = blockIdx.y;

    f32x4 acc[MT][4];
#pragma unroll
    for (int mt = 0; mt < MT; ++mt)
#pragma unroll
        for (int j = 0; j < 4; ++j) acc[mt][j] = (f32x4){0.f, 0.f, 0.f, 0.f};

    const size_t in_base = (size_t)(in_s0 + smp) * 4096 * CI;

    for (int phase = 0; phase < PHASES; ++phase) {
        const int ci0 = phase * CI_BLK;
        __syncthreads();
        for (int idx = tid; idx < 9 * CO_BLK * CI_BLK / 4; idx += 256) {
            int e = idx * 4;
            int tap = e / (CO_BLK * CI_BLK);
            int rem = e - tap * (CO_BLK * CI_BLK);
            int col = rem / CI_BLK;
            int k = rem - col * CI_BLK;
            const ushort4 src = *(const ushort4*)&wpk[((size_t)tap * CO_TOTAL + co0 + col) * CI + ci0 + k];
            *(ushort4*)&s_w[(tap * CO_BLK + col) * PAD + k] = src;
        }
        __syncthreads();

#pragma unroll
        for (int ky = 0; ky < 3; ++ky) {
#pragma unroll
            for (int kx = 0; kx < 3; ++kx) {
                const int tap = ky * 3 + kx;
                bf16x8 bfrag[KC][4];
#pragma unroll
                for (int kc = 0; kc < KC; ++kc) {
#pragma unroll
                    for (int j = 0; j < 4; ++j) {
                        int tile = ng * 16 + wv * 4 + j;
                        int yo = tile / TPR;
                        int xo = (tile % TPR) * 16;
                        int xi = (xo + n16) * S + kx - 1;
                        int yi = yo * S + ky - 1;
                        bool valid = (xi >= 0) && (xi < 64) && (yi >= 0) && (yi < 64);
                        uint4 u;
                        if (valid)
                            u = *(const uint4*)&in[in_base + ((size_t)yi * 64 + xi) * CI + ci0 + kc * 32 + quad * 8];
                        else
                            u = make_uint4(0u, 0u, 0u, 0u);
                        __builtin_memcpy(&bfrag[kc][j], &u, 16);
                    }
                }
#pragma unroll
                for (int kc = 0; kc < KC; ++kc) {
#pragma unroll
                    for (int mt = 0; mt < MT; ++mt) {
                        bf16x8 afrag = *(const bf16x8*)&s_w[(tap * CO_BLK + mt * 16 + n16) * PAD + kc * 32 + quad * 8];
#pragma unroll
                        for (int j = 0; j < 4; ++j)
                            acc[mt][j] = __builtin_amdgcn_mfma_f32_16x16x32_bf16(afrag, bfrag[kc][j], acc[mt][j], 0, 0, 0);
                    }
                }
            }
        }
    }

    const int osmp = out_s0 + smp;
#pragma unroll
    for (int j = 0; j < 4; ++j) {
        int tile = ng * 16 + wv * 4 + j;
        int yo = tile / TPR;
        int xo = (tile % TPR) * 16;
        int pos = yo * WO + xo + n16;
#pragma unroll
        for (int mt = 0; mt < MT; ++mt) {
            int coutb = co0 + mt * 16 + quad * 4;
            ushort4 st;
            st.x = f2bu(acc[mt][j][0]); st.y = f2bu(acc[mt][j][1]);
            st.z = f2bu(acc[mt][j][2]); st.w = f2bu(acc[mt][j][3]);
            *(ushort4*)&((bf16*)out)[((size_t)osmp * HO * WO + pos) * CO_TOTAL + coutb] = st;
        }
    }
}

// ---------------- attention scores + softmax : fused MFMA ----------------
// KQ merged layout: [bt][1024 p][64 c]; K = c 0..31, Q = c 32..63.
__global__ __launch_bounds__(256) void attn_scores_mfma(const bf16* __restrict__ KQ,
                                                        bf16* __restrict__ att) {
    __shared__ float red[4][32][33];
    __shared__ float sc[32][33];
    const int tid = threadIdx.x;
    const int lane = tid & 63;
    const int wv = tid >> 6;
    const int quad = lane >> 4;
    const int n16 = lane & 15;
    const int h = blockIdx.x & 7;
    const int b = blockIdx.x >> 3;
    const size_t base = (size_t)b * 32 * 65536 + (size_t)h * 4;

    f32x4 acc[2][2];
#pragma unroll
    for (int mt = 0; mt < 2; ++mt)
#pragma unroll
        for (int nt = 0; nt < 2; ++nt) acc[mt][nt] = (f32x4){0.f, 0.f, 0.f, 0.f};

    for (int kc = 0; kc < 32; ++kc) {
        const int p0 = wv * 256 + kc * 8 + quad * 2;
        bf16x8 afrag[2], bfrag[2];
#pragma unroll
        for (int mt = 0; mt < 2; ++mt) {
            const bf16* qp = &KQ[base + 32 + (size_t)(mt * 16 + n16) * 65536 + (size_t)p0 * 64];
            uint2 lo = *(const uint2*)qp;
            uint2 hi = *(const uint2*)(qp + 64);
            uint4 u = make_uint4(lo.x, lo.y, hi.x, hi.y);
            __builtin_memcpy(&afrag[mt], &u, 16);
        }
#pragma unroll
        for (int nt = 0; nt < 2; ++nt) {
            const bf16* kp = &KQ[base + (size_t)(nt * 16 + n16) * 65536 + (size_t)p0 * 64];
            uint2 lo = *(const uint2*)kp;
            uint2 hi = *(const uint2*)(kp + 64);
            uint4 u = make_uint4(lo.x, lo.y, hi.x, hi.y);
            __builtin_memcpy(&bfrag[nt], &u, 16);
        }
#pragma unroll
        for (int mt = 0; mt < 2; ++mt)
#pragma unroll
            for (int nt = 0; nt < 2; ++nt)
                acc[mt][nt] = __builtin_amdgcn_mfma_f32_16x16x32_bf16(afrag[mt], bfrag[nt], acc[mt][nt], 0, 0, 0);
    }
#pragma unroll
    for (int mt = 0; mt < 2; ++mt)
#pragma unroll
        for (int nt = 0; nt < 2; ++nt)
#pragma unroll
            for (int r = 0; r < 4; ++r)
                red[wv][mt * 16 + quad * 4 + r][nt * 16 + n16] = acc[mt][nt][r];
    __syncthreads();
    for (int i = tid; i < 1024; i += 256) {
        int t = i >> 5, s = i & 31;
        sc[t][s] = (red[0][t][s] + red[1][t][s] + red[2][t][s] + red[3][t][s]) * (1.0f / 64.0f);
    }
    __syncthreads();
    if (tid < 32) {
        float mx = -1e30f;
        for (int s2 = 0; s2 < 32; ++s2) mx = fmaxf(mx, sc[tid][s2]);
        float sum = 0.f;
        for (int s2 = 0; s2 < 32; ++s2) sum += expf(sc[tid][s2] - mx);
        float inv = 1.f / sum;
        bf16* arow = &att[((size_t)blockIdx.x * 32 + tid) * 32];
        for (int s2 = 0; s2 < 32; ++s2) arow[s2] = f2b(expf(sc[tid][s2] - mx) * inv);
    }
}

// ---------------- y = att @ v : MFMA with fused in-LDS V transpose ----------
__global__ __launch_bounds__(256) void attn_apply_mfma(const bf16* __restrict__ att,
                                                       const bf16* __restrict__ V,
                                                       bf16* __restrict__ Y) {
    __shared__ short vlds[512 * 40];
    __shared__ short ylds[32 * 512];
    const int tid = threadIdx.x;
    const int lane = tid & 63;
    const int wv = tid >> 6;
    const int quad = lane >> 4;
    const int n16 = lane & 15;
    const int pb = blockIdx.x;
    const int b = blockIdx.y;

    for (int l = 0; l < 8; ++l) {
        int u = l * 256 + tid;
        int s = u >> 6;
        int col8 = (u & 63) * 8;
        uint4 v = *(const uint4*)&V[(((size_t)(b * 32 + s) * 4096 + pb * 16) * 32) + col8];
        unsigned short us[8];
        __builtin_memcpy(us, &v, 16);
#pragma unroll
        for (int j = 0; j < 8; ++j) {
            int idx = col8 + j;
            int p = idx >> 5, c = idx & 31;
            int row = ((c >> 2) * 16 + p) * 4 + (c & 3);
            vlds[row * 40 + s] = (short)us[j];
        }
    }
    __syncthreads();

    const int e = wv * 16 + n16;
    const int p = e >> 2, cl = e & 3;
    for (int h = 0; h < 8; ++h) {
        bf16x8 bfrag = *(const bf16x8*)&vlds[(h * 64 + e) * 40 + quad * 8];
        const int c = h * 4 + cl;
#pragma unroll
        for (int mt = 0; mt < 2; ++mt) {
            bf16x8 afrag = *(const bf16x8*)&att[((size_t)(b * 8 + h) * 32 + mt * 16 + n16) * 32 + quad * 8];
            f32x4 d = __builtin_amdgcn_mfma_f32_16x16x32_bf16(afrag, bfrag,
                                                              (f32x4){0.f, 0.f, 0.f, 0.f}, 0, 0, 0);
#pragma unroll
            for (int r = 0; r < 4; ++r) {
                int t = mt * 16 + quad * 4 + r;
                ylds[t * 512 + p * 32 + c] = (short)f2bu(d[r]);
            }
        }
    }
    __syncthreads();

    for (int l = 0; l < 8; ++l) {
        int u = l * 256 + tid;
        int t = u >> 6;
        int col8 = (u & 63) * 8;
        *(uint4*)&Y[(((size_t)(b * 32 + t) * 4096 + pb * 16) * 32) + col8] =
            *(const uint4*)&ylds[t * 512 + col8];
    }
}

extern "C" void kernel_launch(void* const* d_in, const int* in_sizes, int n_in,
                              void* d_out, int out_size, void* d_ws, size_t ws_size,
                              hipStream_t stream) {
    const float* x   = (const float*)d_in[0];
    const float* n1g = (const float*)d_in[1];
    const float* n1b = (const float*)d_in[2];
    const float* n2g = (const float*)d_in[3];
    const float* n2b = (const float*)d_in[4];
    const float* Wk  = (const float*)d_in[5];
    const float* Wq  = (const float*)d_in[6];
    const float* Wv  = (const float*)d_in[7];
    const float* Wo  = (const float*)d_in[8];
    const float* bo  = (const float*)d_in[9];
    const float* Wm1 = (const float*)d_in[10];
    const float* bm1 = (const float*)d_in[11];
    const float* Wm2 = (const float*)d_in[12];
    const float* bm2 = (const float*)d_in[13];

    char* ws = (char*)d_ws;
    const size_t A_OFF = 0;
    const size_t B_OFF = 33554432;
    const size_t D_OFF = 67108864;
    const size_t E_OFF = 67239936;
    const size_t F_OFF = 67461120;
    const size_t C_OFF = 68519936;

    bf16*  xn   = (bf16*)(ws + A_OFF);
    bf16*  Yb   = (bf16*)(ws + A_OFF);
    bf16*  xn2  = (bf16*)(ws + A_OFF);
    bf16*  Vb   = (bf16*)(ws + B_OFF);
    bf16*  X1   = (bf16*)(ws + B_OFF);
    bf16*  attbf = (bf16*)(ws + D_OFF);
    bf16*  wpk_kq = (bf16*)(ws + E_OFF);            // 9*64*32*2 = 36864 B
    bf16*  wpk_v  = (bf16*)(ws + E_OFF + 36864);
    bf16*  wpk_o  = (bf16*)(ws + E_OFF + 55296);
    bf16*  wpk_m1 = (bf16*)(ws + E_OFF + 73728);
    bf16*  wpk_m2 = (bf16*)(ws + E_OFF + 147456);
    float* g2t  = (float*)(ws + F_OFF);
    float* b2t  = (float*)(ws + F_OFF + 524288);
    float2* spart = (float2*)(ws + F_OFF + 1048576);
    float2* stats = (float2*)(ws + F_OFF + 1056768);
    bf16*  KQb  = (bf16*)(ws + C_OFF);              // [128][1024][64] bf16 = 16 MB
    bf16*  Hb   = (bf16*)(ws + C_OFF);

    const size_t HB_PER_SAMPLE = 1048576;
    int chunk = 128;
    if (ws_size < C_OFF + 128 * HB_PER_SAMPLE) {
        size_t avail = (ws_size > C_OFF) ? (ws_size - C_OFF) : HB_PER_SAMPLE;
        chunk = (int)(avail / HB_PER_SAMPLE);
        if (chunk < 1) chunk = 1;
        if (chunk > 128) chunk = 128;
    }

    // 0. pack weights (k,q merged into one 64-CO tensor); transpose LN2 g/b
    pack_w<<<36, 256, 0, stream>>>(Wk, wpk_kq, 32, 32, 64, 0);
    pack_w<<<36, 256, 0, stream>>>(Wq, wpk_kq, 32, 32, 64, 32);
    pack_w<<<36, 256, 0, stream>>>(Wv, wpk_v, 32, 32, 32, 0);
    pack_w<<<36, 256, 0, stream>>>(Wo, wpk_o, 32, 32, 32, 0);
    pack_w<<<144, 256, 0, stream>>>(Wm1, wpk_m1, 128, 32, 128, 0);
    pack_w<<<144, 256, 0, stream>>>(Wm2, wpk_m2, 32, 128, 32, 0);
    gtrans_k<<<1024, 256, 0, stream>>>(n2g, n2b, g2t, b2t);

    // 1. LN1: x (NCHW f32) -> xn (NHWC bf16)
    ln_part<float><<<dim3(8, 128), 256, 0, stream>>>(x, spart);
    ln_fin<<<1, 128, 0, stream>>>(spart, stats);
    ln1_norm_t<<<dim3(32, 128), 256, 0, stream>>>(x, n1g, n1b, stats, xn);
    // 2-3. k+q merged (stride 2, CO=64), v (stride 1 LDS)
    conv_mfma<32, 32, 64, 64, 2, 1><<<dim3(4, 128), 256, 0, stream>>>(xn, wpk_kq, nullptr, nullptr, KQb, 0, 0);
    conv_lds<32, 32, 32, 1><<<dim3(16, 128), 256, 0, stream>>>(xn, wpk_v, nullptr, nullptr, Vb, 0, 0);
    // 5. attention scores + softmax (fused MFMA, merged KQ input)
    attn_scores_mfma<<<32, 256, 0, stream>>>(KQb, attbf);
    // 6. y = att @ v
    attn_apply_mfma<<<dim3(256, 4), 256, 0, stream>>>(attbf, Vb, Yb);
    // 7. Wo conv + bias + residual x -> X1
    conv_lds<32, 32, 32, 2><<<dim3(16, 128), 256, 0, stream>>>(Yb, wpk_o, bo, x, X1, 0, 0);
    // 8. LN2
    ln_part<bf16><<<dim3(8, 128), 256, 0, stream>>>(X1, spart);
    ln_fin<<<1, 128, 0, stream>>>(spart, stats);
    ln2_norm<<<dim3(64, 128), 256, 0, stream>>>(X1, g2t, b2t, stats, xn2);
    // 9-10. mixer (exact R3 configuration — known-good)
    for (int s0 = 0; s0 < 128; s0 += chunk) {
        int n = (128 - s0 < chunk) ? (128 - s0) : chunk;
        conv_lds<32, 128, 64, 3><<<dim3(32, n), 256, 0, stream>>>(xn2, wpk_m1, bm1, nullptr, Hb, s0, 0);
        conv_lds<128, 32, 32, 4><<<dim3(16, n), 256, 0, stream>>>(Hb, wpk_m2, bm2, X1, (float*)d_out, 0, s0);
    }
}

// Round 8
// 504.695 us; speedup vs baseline: 1.2954x; 1.0936x over previous
//
#include <hip/hip_runtime.h>
#include <hip/hip_bf16.h>

using bf16 = __hip_bfloat16;
typedef short bf16x8 __attribute__((ext_vector_type(8)));
typedef float f32x4 __attribute__((ext_vector_type(4)));

__device__ inline float b2f(bf16 h) { return __bfloat162float(h); }
__device__ inline bf16 f2b(float f) { return __float2bfloat16(f); }
__device__ inline unsigned short f2bu(float f) {
    bf16 h = __float2bfloat16(f);
    unsigned short u;
    __builtin_memcpy(&u, &h, 2);
    return u;
}
__device__ inline float su2f(unsigned short u) {
    unsigned v = ((unsigned)u) << 16;
    return __uint_as_float(v);
}
// NewGELU. 0.5*x*(1+tanh(z)) == x * sigmoid(2z); computed with HW exp.
__device__ inline float gelu_new(float x) {
    float x3 = x * x * x;
    float z2 = 1.5957691216057308f * __builtin_fmaf(0.044715f, x3, x); // 2*c*(x+0.044715x^3)
    float e = __expf(-z2);   // v_exp_f32 (quarter-rate)
    return x / (1.0f + e);   // exact limits: e->inf => 0
}

// ---------------- weight pack: [O][I][3][3] f32 -> [tap][CO_TOTAL][CI] bf16 --
__global__ __launch_bounds__(256) void pack_w(const float* __restrict__ w,
                                              bf16* __restrict__ wpk,
                                              int CO, int CI, int CO_TOTAL, int co_off) {
    int i = blockIdx.x * 256 + threadIdx.x;
    int total = CO * CI * 9;
    if (i < total) {
        int tap = i % 9;
        int ci = (i / 9) % CI;
        int co = i / (9 * CI);
        wpk[((size_t)tap * CO_TOTAL + co_off + co) * CI + ci] = f2b(w[i]);
    }
}

// ---------------- g/b transpose NCHW f32 -> NHWC f32 ----------
__global__ __launch_bounds__(256) void gtrans_k(const float* __restrict__ g,
                                                const float* __restrict__ bb,
                                                float* __restrict__ gt,
                                                float* __restrict__ bt) {
    int i = blockIdx.x * 256 + threadIdx.x;
    int sel = i >> 17;
    int o = i & 131071;
    int p = o >> 5, c = o & 31;
    int src = c * 4096 + p;
    if (sel == 0) gt[o] = g[src];
    else          bt[o] = bb[src];
}

// ---------------- LN partial reduce: grid (8, 128) ----------------
template <typename TIN>
__global__ __launch_bounds__(256) void ln_part(const void* __restrict__ xin,
                                               float2* __restrict__ spart) {
    const int tid = threadIdx.x;
    const int sample = blockIdx.y, seg = blockIdx.x;
    const size_t base = (size_t)sample * 131072 + seg * 16384;
    float sum = 0.f, ss = 0.f;
    if constexpr (sizeof(TIN) == 4) {
        const float4* p = (const float4*)((const float*)xin + base);
        for (int l = 0; l < 16; ++l) {
            float4 v = p[l * 256 + tid];
            sum += v.x + v.y + v.z + v.w;
            ss += v.x * v.x + v.y * v.y + v.z * v.z + v.w * v.w;
        }
    } else {
        const uint4* p = (const uint4*)((const bf16*)xin + base);
        for (int l = 0; l < 8; ++l) {
            uint4 u = p[l * 256 + tid];
            unsigned w[4] = {u.x, u.y, u.z, u.w};
#pragma unroll
            for (int j = 0; j < 4; ++j) {
                float lo = __uint_as_float(w[j] << 16);
                float hi = __uint_as_float(w[j] & 0xffff0000u);
                sum += lo + hi;
                ss += lo * lo + hi * hi;
            }
        }
    }
    __shared__ float rs[256], rs2[256];
    rs[tid] = sum; rs2[tid] = ss;
    __syncthreads();
    for (int off = 128; off > 0; off >>= 1) {
        if (tid < off) { rs[tid] += rs[tid + off]; rs2[tid] += rs2[tid + off]; }
        __syncthreads();
    }
    if (tid == 0) spart[sample * 8 + seg] = make_float2(rs[0], rs2[0]);
}

// ---------------- LN finalize ----------------
__global__ __launch_bounds__(128) void ln_fin(const float2* __restrict__ spart,
                                              float2* __restrict__ stats) {
    int t = threadIdx.x;
    float s = 0.f, ss = 0.f;
    for (int j = 0; j < 8; ++j) {
        float2 v = spart[t * 8 + j];
        s += v.x; ss += v.y;
    }
    float m = s / 131072.f;
    float var = ss / 131072.f - m * m;
    stats[t] = make_float2(m, rsqrtf(var + 1e-5f));
}

// ---------------- LN1 normalize + NCHW->NHWC transpose ----------------
__global__ __launch_bounds__(256) void ln1_norm_t(const float* __restrict__ x,
                                                  const float* __restrict__ g,
                                                  const float* __restrict__ bb,
                                                  const float2* __restrict__ stats,
                                                  bf16* __restrict__ out) {
    __shared__ float tile[32][129];
    const int tid = threadIdx.x;
    const int sample = blockIdx.y;
    const int p0 = blockIdx.x * 128;
    float2 st = stats[sample];
    const float m = st.x, r = st.y;
    const size_t xb = (size_t)sample * 131072;
    for (int k = 0; k < 16; ++k) {
        int idx = k * 256 + tid;
        int c = idx >> 7, p = idx & 127;
        int gi = c * 4096 + p0 + p;
        float v = x[xb + gi];
        tile[c][p] = (v - m) * r * g[gi] + bb[gi];
    }
    __syncthreads();
    for (int k = 0; k < 8; ++k) {
        int idx = k * 256 + tid;
        int p = idx >> 4, c2 = (idx & 15) * 2;
        unsigned lo = (unsigned)f2bu(tile[c2][p]);
        unsigned hi = (unsigned)f2bu(tile[c2 + 1][p]);
        *(unsigned*)&out[xb + (size_t)(p0 + p) * 32 + c2] = lo | (hi << 16);
    }
}

// ---------------- LN2 normalize, NHWC linear ----------------
__global__ __launch_bounds__(256) void ln2_norm(const bf16* __restrict__ xin,
                                                const float* __restrict__ gt,
                                                const float* __restrict__ bt,
                                                const float2* __restrict__ stats,
                                                bf16* __restrict__ out) {
    const int tid = threadIdx.x;
    const int sample = blockIdx.y;
    float2 st = stats[sample];
    const float m = st.x, r = st.y;
    int i0 = (blockIdx.x * 256 + tid) * 8;
    const size_t base = (size_t)sample * 131072 + i0;
    uint4 u = *(const uint4*)&xin[base];
    float4 g0 = *(const float4*)&gt[i0];
    float4 g1 = *(const float4*)&gt[i0 + 4];
    float4 b0 = *(const float4*)&bt[i0];
    float4 b1 = *(const float4*)&bt[i0 + 4];
    unsigned w[4] = {u.x, u.y, u.z, u.w};
    float gv[8] = {g0.x, g0.y, g0.z, g0.w, g1.x, g1.y, g1.z, g1.w};
    float bv[8] = {b0.x, b0.y, b0.z, b0.w, b1.x, b1.y, b1.z, b1.w};
    unsigned o[4];
#pragma unroll
    for (int j = 0; j < 4; ++j) {
        float lo = __uint_as_float(w[j] << 16);
        float hi = __uint_as_float(w[j] & 0xffff0000u);
        lo = (lo - m) * r * gv[2 * j] + bv[2 * j];
        hi = (hi - m) * r * gv[2 * j + 1] + bv[2 * j + 1];
        o[j] = (unsigned)f2bu(lo) | ((unsigned)f2bu(hi) << 16);
    }
    uint4 st4 = make_uint4(o[0], o[1], o[2], o[3]);
    *(uint4*)&out[base] = st4;
}

// ---------------- stride-1 conv: LDS staged; ROWS rows per block ------------
// ROWS=4 -> 256 threads (V/Wo). ROWS=8 -> 512 threads (mixer): LDS grows
// sub-linearly (halo 10 rows for 8 outputs vs 6 for 4), still 2 blocks/CU
// => 16 waves/CU instead of 8..12 — doubles latency-hiding for the
// latency-bound mixer convs; halo refetch drops 1.5x -> 1.25x.
template <int CI, int CO_TOTAL, int CO_BLK, int EPI, int ROWS = 4>
__global__ __launch_bounds__(ROWS * 64) void conv_lds(const bf16* __restrict__ in,
                                                      const bf16* __restrict__ wpk,
                                                      const float* __restrict__ bias,
                                                      const void* __restrict__ res,
                                                      void* __restrict__ out,
                                                      int in_s0, int out_s0) {
    constexpr int CHUNKS = CI / 32;
    constexpr int MT = CO_BLK / 16;
    constexpr int NG = 64 / ROWS;
    constexpr int NT = ROWS * 64;
    constexpr int HR = ROWS + 2;

    __shared__ short s_in[HR * 66 * 32];
    __shared__ short s_w[9 * CO_BLK * 32];

    const int tid = threadIdx.x;
    const int lane = tid & 63;
    const int wv = tid >> 6;
    const int quad = lane >> 4;
    const int n16 = lane & 15;

    const int ng = blockIdx.x % NG;
    const int cg = blockIdx.x / NG;
    const int co0 = cg * CO_BLK;
    const int smp = blockIdx.y;
    const int y0 = ng * ROWS;

    f32x4 acc[MT][4];
#pragma unroll
    for (int mt = 0; mt < MT; ++mt)
#pragma unroll
        for (int j = 0; j < 4; ++j) acc[mt][j] = (f32x4){0.f, 0.f, 0.f, 0.f};

    const size_t in_base = (size_t)(in_s0 + smp) * 4096 * CI;

    for (int chunk = 0; chunk < CHUNKS; ++chunk) {
        const int ci0 = chunk * 32;
        __syncthreads();
        for (int i = tid; i < HR * 66 * 4; i += NT) {
            int sub = i & 3;
            int x = (i >> 2) % 66;
            int row = i / 264;
            int y = y0 + row - 1;
            int xg = x - 1;
            uint4 u = make_uint4(0u, 0u, 0u, 0u);
            if (y >= 0 && y < 64 && xg >= 0 && xg < 64)
                u = *(const uint4*)&in[in_base + ((size_t)y * 64 + xg) * CI + ci0 + sub * 8];
            int ps = sub ^ (x & 3) ^ ((x >> 2) & 1);
            *(uint4*)&s_in[(row * 66 + x) * 32 + ps * 8] = u;
        }
        for (int i = tid; i < 9 * CO_BLK * 4; i += NT) {
            int sub = i & 3;
            int co = (i >> 2) % CO_BLK;
            int tap = i / (CO_BLK * 4);
            uint4 u = *(const uint4*)&wpk[((size_t)tap * CO_TOTAL + co0 + co) * CI + ci0 + sub * 8];
            int ps = sub ^ (co & 3) ^ ((co >> 2) & 1);
            *(uint4*)&s_w[(tap * CO_BLK + co) * 32 + ps * 8] = u;
        }
        __syncthreads();

#pragma unroll
        for (int ky = 0; ky < 3; ++ky) {
#pragma unroll
            for (int kx = 0; kx < 3; ++kx) {
                const int tap = ky * 3 + kx;
                bf16x8 bfrag[4];
#pragma unroll
                for (int j = 0; j < 4; ++j) {
                    int x = j * 16 + n16 + kx;
                    int ps = quad ^ (x & 3) ^ ((x >> 2) & 1);
                    bfrag[j] = *(const bf16x8*)&s_in[((wv + ky) * 66 + x) * 32 + ps * 8];
                }
#pragma unroll
                for (int mt = 0; mt < MT; ++mt) {
                    int mrow = mt * 16 + n16;
                    int ps = quad ^ (mrow & 3) ^ ((mrow >> 2) & 1);
                    bf16x8 afrag = *(const bf16x8*)&s_w[(tap * CO_BLK + mrow) * 32 + ps * 8];
#pragma unroll
                    for (int j = 0; j < 4; ++j)
                        acc[mt][j] = __builtin_amdgcn_mfma_f32_16x16x32_bf16(afrag, bfrag[j], acc[mt][j], 0, 0, 0);
                }
            }
        }
    }

    const int osmp = out_s0 + smp;
#pragma unroll
    for (int j = 0; j < 4; ++j) {
        int pos = (y0 + wv) * 64 + j * 16 + n16;
#pragma unroll
        for (int mt = 0; mt < MT; ++mt) {
            int coutb = co0 + mt * 16 + quad * 4;
            float b0 = 0.f, b1 = 0.f, b2 = 0.f, b3 = 0.f;
            if constexpr (EPI != 1) {
                float4 bv = *(const float4*)&bias[coutb];
                b0 = bv.x; b1 = bv.y; b2 = bv.z; b3 = bv.w;
            }
            float v0 = acc[mt][j][0] + b0;
            float v1 = acc[mt][j][1] + b1;
            float v2 = acc[mt][j][2] + b2;
            float v3 = acc[mt][j][3] + b3;
            if constexpr (EPI == 1 || EPI == 2 || EPI == 3) {
                if constexpr (EPI == 2) {
                    const float* xr = (const float*)res + (size_t)osmp * 131072 + (size_t)coutb * 4096 + pos;
                    v0 += xr[0]; v1 += xr[4096]; v2 += xr[8192]; v3 += xr[12288];
                } else if constexpr (EPI == 3) {
                    v0 = gelu_new(v0); v1 = gelu_new(v1); v2 = gelu_new(v2); v3 = gelu_new(v3);
                }
                ushort4 st;
                st.x = f2bu(v0); st.y = f2bu(v1); st.z = f2bu(v2); st.w = f2bu(v3);
                *(ushort4*)&((bf16*)out)[((size_t)osmp * 4096 + pos) * CO_TOTAL + coutb] = st;
            } else {
                ushort4 rv = *(const ushort4*)&((const bf16*)res)[((size_t)osmp * 4096 + pos) * 32 + coutb];
                v0 += su2f(rv.x); v1 += su2f(rv.y); v2 += su2f(rv.z); v3 += su2f(rv.w);
                float* op = (float*)out + (size_t)osmp * 131072 + (size_t)coutb * 4096 + pos;
                op[0] = v0; op[4096] = v1; op[8192] = v2; op[12288] = v3;
            }
        }
    }
}

// ---------------- stride-2 conv (k,q merged: CO_TOTAL=64) ----------------
template <int CI, int CI_BLK, int CO_TOTAL, int CO_BLK, int S, int EPI>
__global__ __launch_bounds__(256) void conv_mfma(const bf16* __restrict__ in,
                                                 const bf16* __restrict__ wpk,
                                                 const float* __restrict__ bias,
                                                 const void* __restrict__ res,
                                                 void* __restrict__ out,
                                                 int in_s0, int out_s0) {
    constexpr int WO = 64 / S;
    constexpr int HO = 64 / S;
    constexpr int NG = (HO * WO) / 256;
    constexpr int TPR = WO / 16;
    constexpr int MT = CO_BLK / 16;
    constexpr int PHASES = CI / CI_BLK;
    constexpr int KC = CI_BLK / 32;
    constexpr int PAD = CI_BLK + 8;

    __shared__ short s_w[9 * CO_BLK * PAD];

    const int tid = threadIdx.x;
    const int lane = tid & 63;
    const int wv = tid >> 6;
    const int quad = lane >> 4;
    const int n16 = lane & 15;

    const int ng = blockIdx.x % NG;
    const int cg = blockIdx.x / NG;
    const int co0 = cg * CO_BLK;
    const int smp = blockIdx.y;

    f32x4 acc[MT][4];
#pragma unroll
    for (int mt = 0; mt < MT; ++mt)
#pragma unroll
        for (int j = 0; j < 4; ++j) acc[mt][j] = (f32x4){0.f, 0.f, 0.f, 0.f};

    const size_t in_base = (size_t)(in_s0 + smp) * 4096 * CI;

    for (int phase = 0; phase < PHASES; ++phase) {
        const int ci0 = phase * CI_BLK;
        __syncthreads();
        for (int idx = tid; idx < 9 * CO_BLK * CI_BLK / 4; idx += 256) {
            int e = idx * 4;
            int tap = e / (CO_BLK * CI_BLK);
            int rem = e - tap * (CO_BLK * CI_BLK);
            int col = rem / CI_BLK;
            int k = rem - col * CI_BLK;
            const ushort4 src = *(const ushort4*)&wpk[((size_t)tap * CO_TOTAL + co0 + col) * CI + ci0 + k];
            *(ushort4*)&s_w[(tap * CO_BLK + col) * PAD + k] = src;
        }
        __syncthreads();

#pragma unroll
        for (int ky = 0; ky < 3; ++ky) {
#pragma unroll
            for (int kx = 0; kx < 3; ++kx) {
                const int tap = ky * 3 + kx;
                bf16x8 bfrag[KC][4];
#pragma unroll
                for (int kc = 0; kc < KC; ++kc) {
#pragma unroll
                    for (int j = 0; j < 4; ++j) {
                        int tile = ng * 16 + wv * 4 + j;
                        int yo = tile / TPR;
                        int xo = (tile % TPR) * 16;
                        int xi = (xo + n16) * S + kx - 1;
                        int yi = yo * S + ky - 1;
                        bool valid = (xi >= 0) && (xi < 64) && (yi >= 0) && (yi < 64);
                        uint4 u;
                        if (valid)
                            u = *(const uint4*)&in[in_base + ((size_t)yi * 64 + xi) * CI + ci0 + kc * 32 + quad * 8];
                        else
                            u = make_uint4(0u, 0u, 0u, 0u);
                        __builtin_memcpy(&bfrag[kc][j], &u, 16);
                    }
                }
#pragma unroll
                for (int kc = 0; kc < KC; ++kc) {
#pragma unroll
                    for (int mt = 0; mt < MT; ++mt) {
                        bf16x8 afrag = *(const bf16x8*)&s_w[(tap * CO_BLK + mt * 16 + n16) * PAD + kc * 32 + quad * 8];
#pragma unroll
                        for (int j = 0; j < 4; ++j)
                            acc[mt][j] = __builtin_amdgcn_mfma_f32_16x16x32_bf16(afrag, bfrag[kc][j], acc[mt][j], 0, 0, 0);
                    }
                }
            }
        }
    }

    const int osmp = out_s0 + smp;
#pragma unroll
    for (int j = 0; j < 4; ++j) {
        int tile = ng * 16 + wv * 4 + j;
        int yo = tile / TPR;
        int xo = (tile % TPR) * 16;
        int pos = yo * WO + xo + n16;
#pragma unroll
        for (int mt = 0; mt < MT; ++mt) {
            int coutb = co0 + mt * 16 + quad * 4;
            ushort4 st;
            st.x = f2bu(acc[mt][j][0]); st.y = f2bu(acc[mt][j][1]);
            st.z = f2bu(acc[mt][j][2]); st.w = f2bu(acc[mt][j][3]);
            *(ushort4*)&((bf16*)out)[((size_t)osmp * HO * WO + pos) * CO_TOTAL + coutb] = st;
        }
    }
}

// ---------------- attention scores + softmax : fused MFMA ----------------
// KQ merged layout: [bt][1024 p][64 c]; K = c 0..31, Q = c 32..63.
__global__ __launch_bounds__(256) void attn_scores_mfma(const bf16* __restrict__ KQ,
                                                        bf16* __restrict__ att) {
    __shared__ float red[4][32][33];
    __shared__ float sc[32][33];
    const int tid = threadIdx.x;
    const int lane = tid & 63;
    const int wv = tid >> 6;
    const int quad = lane >> 4;
    const int n16 = lane & 15;
    const int h = blockIdx.x & 7;
    const int b = blockIdx.x >> 3;
    const size_t base = (size_t)b * 32 * 65536 + (size_t)h * 4;

    f32x4 acc[2][2];
#pragma unroll
    for (int mt = 0; mt < 2; ++mt)
#pragma unroll
        for (int nt = 0; nt < 2; ++nt) acc[mt][nt] = (f32x4){0.f, 0.f, 0.f, 0.f};

    for (int kc = 0; kc < 32; ++kc) {
        const int p0 = wv * 256 + kc * 8 + quad * 2;
        bf16x8 afrag[2], bfrag[2];
#pragma unroll
        for (int mt = 0; mt < 2; ++mt) {
            const bf16* qp = &KQ[base + 32 + (size_t)(mt * 16 + n16) * 65536 + (size_t)p0 * 64];
            uint2 lo = *(const uint2*)qp;
            uint2 hi = *(const uint2*)(qp + 64);
            uint4 u = make_uint4(lo.x, lo.y, hi.x, hi.y);
            __builtin_memcpy(&afrag[mt], &u, 16);
        }
#pragma unroll
        for (int nt = 0; nt < 2; ++nt) {
            const bf16* kp = &KQ[base + (size_t)(nt * 16 + n16) * 65536 + (size_t)p0 * 64];
            uint2 lo = *(const uint2*)kp;
            uint2 hi = *(const uint2*)(kp + 64);
            uint4 u = make_uint4(lo.x, lo.y, hi.x, hi.y);
            __builtin_memcpy(&bfrag[nt], &u, 16);
        }
#pragma unroll
        for (int mt = 0; mt < 2; ++mt)
#pragma unroll
            for (int nt = 0; nt < 2; ++nt)
                acc[mt][nt] = __builtin_amdgcn_mfma_f32_16x16x32_bf16(afrag[mt], bfrag[nt], acc[mt][nt], 0, 0, 0);
    }
#pragma unroll
    for (int mt = 0; mt < 2; ++mt)
#pragma unroll
        for (int nt = 0; nt < 2; ++nt)
#pragma unroll
            for (int r = 0; r < 4; ++r)
                red[wv][mt * 16 + quad * 4 + r][nt * 16 + n16] = acc[mt][nt][r];
    __syncthreads();
    for (int i = tid; i < 1024; i += 256) {
        int t = i >> 5, s = i & 31;
        sc[t][s] = (red[0][t][s] + red[1][t][s] + red[2][t][s] + red[3][t][s]) * (1.0f / 64.0f);
    }
    __syncthreads();
    if (tid < 32) {
        float mx = -1e30f;
        for (int s2 = 0; s2 < 32; ++s2) mx = fmaxf(mx, sc[tid][s2]);
        float sum = 0.f;
        for (int s2 = 0; s2 < 32; ++s2) sum += expf(sc[tid][s2] - mx);
        float inv = 1.f / sum;
        bf16* arow = &att[((size_t)blockIdx.x * 32 + tid) * 32];
        for (int s2 = 0; s2 < 32; ++s2) arow[s2] = f2b(expf(sc[tid][s2] - mx) * inv);
    }
}

// ---------------- y = att @ v : MFMA with fused in-LDS V transpose ----------
__global__ __launch_bounds__(256) void attn_apply_mfma(const bf16* __restrict__ att,
                                                       const bf16* __restrict__ V,
                                                       bf16* __restrict__ Y) {
    __shared__ short vlds[512 * 40];
    __shared__ short ylds[32 * 512];
    const int tid = threadIdx.x;
    const int lane = tid & 63;
    const int wv = tid >> 6;
    const int quad = lane >> 4;
    const int n16 = lane & 15;
    const int pb = blockIdx.x;
    const int b = blockIdx.y;

    for (int l = 0; l < 8; ++l) {
        int u = l * 256 + tid;
        int s = u >> 6;
        int col8 = (u & 63) * 8;
        uint4 v = *(const uint4*)&V[(((size_t)(b * 32 + s) * 4096 + pb * 16) * 32) + col8];
        unsigned short us[8];
        __builtin_memcpy(us, &v, 16);
#pragma unroll
        for (int j = 0; j < 8; ++j) {
            int idx = col8 + j;
            int p = idx >> 5, c = idx & 31;
            int row = ((c >> 2) * 16 + p) * 4 + (c & 3);
            vlds[row * 40 + s] = (short)us[j];
        }
    }
    __syncthreads();

    const int e = wv * 16 + n16;
    const int p = e >> 2, cl = e & 3;
    for (int h = 0; h < 8; ++h) {
        bf16x8 bfrag = *(const bf16x8*)&vlds[(h * 64 + e) * 40 + quad * 8];
        const int c = h * 4 + cl;
#pragma unroll
        for (int mt = 0; mt < 2; ++mt) {
            bf16x8 afrag = *(const bf16x8*)&att[((size_t)(b * 8 + h) * 32 + mt * 16 + n16) * 32 + quad * 8];
            f32x4 d = __builtin_amdgcn_mfma_f32_16x16x32_bf16(afrag, bfrag,
                                                              (f32x4){0.f, 0.f, 0.f, 0.f}, 0, 0, 0);
#pragma unroll
            for (int r = 0; r < 4; ++r) {
                int t = mt * 16 + quad * 4 + r;
                ylds[t * 512 + p * 32 + c] = (short)f2bu(d[r]);
            }
        }
    }
    __syncthreads();

    for (int l = 0; l < 8; ++l) {
        int u = l * 256 + tid;
        int t = u >> 6;
        int col8 = (u & 63) * 8;
        *(uint4*)&Y[(((size_t)(b * 32 + t) * 4096 + pb * 16) * 32) + col8] =
            *(const uint4*)&ylds[t * 512 + col8];
    }
}

extern "C" void kernel_launch(void* const* d_in, const int* in_sizes, int n_in,
                              void* d_out, int out_size, void* d_ws, size_t ws_size,
                              hipStream_t stream) {
    const float* x   = (const float*)d_in[0];
    const float* n1g = (const float*)d_in[1];
    const float* n1b = (const float*)d_in[2];
    const float* n2g = (const float*)d_in[3];
    const float* n2b = (const float*)d_in[4];
    const float* Wk  = (const float*)d_in[5];
    const float* Wq  = (const float*)d_in[6];
    const float* Wv  = (const float*)d_in[7];
    const float* Wo  = (const float*)d_in[8];
    const float* bo  = (const float*)d_in[9];
    const float* Wm1 = (const float*)d_in[10];
    const float* bm1 = (const float*)d_in[11];
    const float* Wm2 = (const float*)d_in[12];
    const float* bm2 = (const float*)d_in[13];

    char* ws = (char*)d_ws;
    const size_t A_OFF = 0;
    const size_t B_OFF = 33554432;
    const size_t D_OFF = 67108864;
    const size_t E_OFF = 67239936;
    const size_t F_OFF = 67461120;
    const size_t C_OFF = 68519936;

    bf16*  xn   = (bf16*)(ws + A_OFF);
    bf16*  Yb   = (bf16*)(ws + A_OFF);
    bf16*  xn2  = (bf16*)(ws + A_OFF);
    bf16*  Vb   = (bf16*)(ws + B_OFF);
    bf16*  X1   = (bf16*)(ws + B_OFF);
    bf16*  attbf = (bf16*)(ws + D_OFF);
    bf16*  wpk_kq = (bf16*)(ws + E_OFF);            // 9*64*32*2 = 36864 B
    bf16*  wpk_v  = (bf16*)(ws + E_OFF + 36864);
    bf16*  wpk_o  = (bf16*)(ws + E_OFF + 55296);
    bf16*  wpk_m1 = (bf16*)(ws + E_OFF + 73728);
    bf16*  wpk_m2 = (bf16*)(ws + E_OFF + 147456);
    float* g2t  = (float*)(ws + F_OFF);
    float* b2t  = (float*)(ws + F_OFF + 524288);
    float2* spart = (float2*)(ws + F_OFF + 1048576);
    float2* stats = (float2*)(ws + F_OFF + 1056768);
    bf16*  KQb  = (bf16*)(ws + C_OFF);              // [128][1024][64] bf16 = 16 MB
    bf16*  Hb   = (bf16*)(ws + C_OFF);

    const size_t HB_PER_SAMPLE = 1048576;
    int chunk = 128;
    if (ws_size < C_OFF + 128 * HB_PER_SAMPLE) {
        size_t avail = (ws_size > C_OFF) ? (ws_size - C_OFF) : HB_PER_SAMPLE;
        chunk = (int)(avail / HB_PER_SAMPLE);
        if (chunk < 1) chunk = 1;
        if (chunk > 128) chunk = 128;
    }

    // 0. pack weights (k,q merged into one 64-CO tensor); transpose LN2 g/b
    pack_w<<<36, 256, 0, stream>>>(Wk, wpk_kq, 32, 32, 64, 0);
    pack_w<<<36, 256, 0, stream>>>(Wq, wpk_kq, 32, 32, 64, 32);
    pack_w<<<36, 256, 0, stream>>>(Wv, wpk_v, 32, 32, 32, 0);
    pack_w<<<36, 256, 0, stream>>>(Wo, wpk_o, 32, 32, 32, 0);
    pack_w<<<144, 256, 0, stream>>>(Wm1, wpk_m1, 128, 32, 128, 0);
    pack_w<<<144, 256, 0, stream>>>(Wm2, wpk_m2, 32, 128, 32, 0);
    gtrans_k<<<1024, 256, 0, stream>>>(n2g, n2b, g2t, b2t);

    // 1. LN1: x (NCHW f32) -> xn (NHWC bf16)
    ln_part<float><<<dim3(8, 128), 256, 0, stream>>>(x, spart);
    ln_fin<<<1, 128, 0, stream>>>(spart, stats);
    ln1_norm_t<<<dim3(32, 128), 256, 0, stream>>>(x, n1g, n1b, stats, xn);
    // 2-3. k+q merged (stride 2, CO=64), v (stride 1 LDS, 4-row control)
    conv_mfma<32, 32, 64, 64, 2, 1><<<dim3(4, 128), 256, 0, stream>>>(xn, wpk_kq, nullptr, nullptr, KQb, 0, 0);
    conv_lds<32, 32, 32, 1, 4><<<dim3(16, 128), 256, 0, stream>>>(xn, wpk_v, nullptr, nullptr, Vb, 0, 0);
    // 5. attention scores + softmax (fused MFMA, merged KQ input)
    attn_scores_mfma<<<32, 256, 0, stream>>>(KQb, attbf);
    // 6. y = att @ v
    attn_apply_mfma<<<dim3(256, 4), 256, 0, stream>>>(attbf, Vb, Yb);
    // 7. Wo conv + bias + residual x -> X1 (4-row control)
    conv_lds<32, 32, 32, 2, 4><<<dim3(16, 128), 256, 0, stream>>>(Yb, wpk_o, bo, x, X1, 0, 0);
    // 8. LN2
    ln_part<bf16><<<dim3(8, 128), 256, 0, stream>>>(X1, spart);
    ln_fin<<<1, 128, 0, stream>>>(spart, stats);
    ln2_norm<<<dim3(64, 128), 256, 0, stream>>>(X1, g2t, b2t, stats, xn2);
    // 9-10. mixer: 8-row / 512-thread blocks -> 16 waves/CU (experiment)
    for (int s0 = 0; s0 < 128; s0 += chunk) {
        int n = (128 - s0 < chunk) ? (128 - s0) : chunk;
        conv_lds<32, 128, 64, 3, 8><<<dim3(16, n), 512, 0, stream>>>(xn2, wpk_m1, bm1, nullptr, Hb, s0, 0);
        conv_lds<128, 32, 32, 4, 8><<<dim3(8, n), 512, 0, stream>>>(Hb, wpk_m2, bm2, X1, (float*)d_out, 0, s0);
    }
}

// Round 9
// 486.001 us; speedup vs baseline: 1.3452x; 1.0385x over previous
//
#include <hip/hip_runtime.h>
#include <hip/hip_bf16.h>

using bf16 = __hip_bfloat16;
typedef short bf16x8 __attribute__((ext_vector_type(8)));
typedef float f32x4 __attribute__((ext_vector_type(4)));

#define AS1 __attribute__((address_space(1)))
#define AS3 __attribute__((address_space(3)))

__device__ inline float b2f(bf16 h) { return __bfloat162float(h); }
__device__ inline bf16 f2b(float f) { return __float2bfloat16(f); }
__device__ inline unsigned short f2bu(float f) {
    bf16 h = __float2bfloat16(f);
    unsigned short u;
    __builtin_memcpy(&u, &h, 2);
    return u;
}
__device__ inline float su2f(unsigned short u) {
    unsigned v = ((unsigned)u) << 16;
    return __uint_as_float(v);
}
// async global->LDS, 16B per lane, LDS dest = wave-uniform base + lane*16
__device__ inline void gload16(const bf16* gp, short* lp) {
    __builtin_amdgcn_global_load_lds((const AS1 void*)gp, (AS3 void*)lp, 16, 0, 0);
}
// NewGELU. 0.5*x*(1+tanh(z)) == x * sigmoid(2z); computed with HW exp.
__device__ inline float gelu_new(float x) {
    float x3 = x * x * x;
    float z2 = 1.5957691216057308f * __builtin_fmaf(0.044715f, x3, x);
    float e = __expf(-z2);
    return x / (1.0f + e);
}

// ---------------- zero page (halo source for global_load_lds) ----------------
__global__ __launch_bounds__(64) void zero_page(float* z) { z[threadIdx.x] = 0.f; }

// ---------------- weight pack: [O][I][3][3] f32 -> [tap][CO_TOTAL][CI] bf16 --
__global__ __launch_bounds__(256) void pack_w(const float* __restrict__ w,
                                              bf16* __restrict__ wpk,
                                              int CO, int CI, int CO_TOTAL, int co_off) {
    int i = blockIdx.x * 256 + threadIdx.x;
    int total = CO * CI * 9;
    if (i < total) {
        int tap = i % 9;
        int ci = (i / 9) % CI;
        int co = i / (9 * CI);
        wpk[((size_t)tap * CO_TOTAL + co_off + co) * CI + ci] = f2b(w[i]);
    }
}

// ---------------- g/b transpose NCHW f32 -> NHWC f32 ----------
__global__ __launch_bounds__(256) void gtrans_k(const float* __restrict__ g,
                                                const float* __restrict__ bb,
                                                float* __restrict__ gt,
                                                float* __restrict__ bt) {
    int i = blockIdx.x * 256 + threadIdx.x;
    int sel = i >> 17;
    int o = i & 131071;
    int p = o >> 5, c = o & 31;
    int src = c * 4096 + p;
    if (sel == 0) gt[o] = g[src];
    else          bt[o] = bb[src];
}

// ---------------- LN partial reduce: grid (8, 128) ----------------
template <typename TIN>
__global__ __launch_bounds__(256) void ln_part(const void* __restrict__ xin,
                                               float2* __restrict__ spart) {
    const int tid = threadIdx.x;
    const int sample = blockIdx.y, seg = blockIdx.x;
    const size_t base = (size_t)sample * 131072 + seg * 16384;
    float sum = 0.f, ss = 0.f;
    if constexpr (sizeof(TIN) == 4) {
        const float4* p = (const float4*)((const float*)xin + base);
        for (int l = 0; l < 16; ++l) {
            float4 v = p[l * 256 + tid];
            sum += v.x + v.y + v.z + v.w;
            ss += v.x * v.x + v.y * v.y + v.z * v.z + v.w * v.w;
        }
    } else {
        const uint4* p = (const uint4*)((const bf16*)xin + base);
        for (int l = 0; l < 8; ++l) {
            uint4 u = p[l * 256 + tid];
            unsigned w[4] = {u.x, u.y, u.z, u.w};
#pragma unroll
            for (int j = 0; j < 4; ++j) {
                float lo = __uint_as_float(w[j] << 16);
                float hi = __uint_as_float(w[j] & 0xffff0000u);
                sum += lo + hi;
                ss += lo * lo + hi * hi;
            }
        }
    }
    __shared__ float rs[256], rs2[256];
    rs[tid] = sum; rs2[tid] = ss;
    __syncthreads();
    for (int off = 128; off > 0; off >>= 1) {
        if (tid < off) { rs[tid] += rs[tid + off]; rs2[tid] += rs2[tid + off]; }
        __syncthreads();
    }
    if (tid == 0) spart[sample * 8 + seg] = make_float2(rs[0], rs2[0]);
}

// ---------------- LN finalize ----------------
__global__ __launch_bounds__(128) void ln_fin(const float2* __restrict__ spart,
                                              float2* __restrict__ stats) {
    int t = threadIdx.x;
    float s = 0.f, ss = 0.f;
    for (int j = 0; j < 8; ++j) {
        float2 v = spart[t * 8 + j];
        s += v.x; ss += v.y;
    }
    float m = s / 131072.f;
    float var = ss / 131072.f - m * m;
    stats[t] = make_float2(m, rsqrtf(var + 1e-5f));
}

// ---------------- LN1 normalize + NCHW->NHWC transpose ----------------
__global__ __launch_bounds__(256) void ln1_norm_t(const float* __restrict__ x,
                                                  const float* __restrict__ g,
                                                  const float* __restrict__ bb,
                                                  const float2* __restrict__ stats,
                                                  bf16* __restrict__ out) {
    __shared__ float tile[32][129];
    const int tid = threadIdx.x;
    const int sample = blockIdx.y;
    const int p0 = blockIdx.x * 128;
    float2 st = stats[sample];
    const float m = st.x, r = st.y;
    const size_t xb = (size_t)sample * 131072;
    for (int k = 0; k < 16; ++k) {
        int idx = k * 256 + tid;
        int c = idx >> 7, p = idx & 127;
        int gi = c * 4096 + p0 + p;
        float v = x[xb + gi];
        tile[c][p] = (v - m) * r * g[gi] + bb[gi];
    }
    __syncthreads();
    for (int k = 0; k < 8; ++k) {
        int idx = k * 256 + tid;
        int p = idx >> 4, c2 = (idx & 15) * 2;
        unsigned lo = (unsigned)f2bu(tile[c2][p]);
        unsigned hi = (unsigned)f2bu(tile[c2 + 1][p]);
        *(unsigned*)&out[xb + (size_t)(p0 + p) * 32 + c2] = lo | (hi << 16);
    }
}

// ---------------- LN2 normalize, NHWC linear ----------------
__global__ __launch_bounds__(256) void ln2_norm(const bf16* __restrict__ xin,
                                                const float* __restrict__ gt,
                                                const float* __restrict__ bt,
                                                const float2* __restrict__ stats,
                                                bf16* __restrict__ out) {
    const int tid = threadIdx.x;
    const int sample = blockIdx.y;
    float2 st = stats[sample];
    const float m = st.x, r = st.y;
    int i0 = (blockIdx.x * 256 + tid) * 8;
    const size_t base = (size_t)sample * 131072 + i0;
    uint4 u = *(const uint4*)&xin[base];
    float4 g0 = *(const float4*)&gt[i0];
    float4 g1 = *(const float4*)&gt[i0 + 4];
    float4 b0 = *(const float4*)&bt[i0];
    float4 b1 = *(const float4*)&bt[i0 + 4];
    unsigned w[4] = {u.x, u.y, u.z, u.w};
    float gv[8] = {g0.x, g0.y, g0.z, g0.w, g1.x, g1.y, g1.z, g1.w};
    float bv[8] = {b0.x, b0.y, b0.z, b0.w, b1.x, b1.y, b1.z, b1.w};
    unsigned o[4];
#pragma unroll
    for (int j = 0; j < 4; ++j) {
        float lo = __uint_as_float(w[j] << 16);
        float hi = __uint_as_float(w[j] & 0xffff0000u);
        lo = (lo - m) * r * gv[2 * j] + bv[2 * j];
        hi = (hi - m) * r * gv[2 * j + 1] + bv[2 * j + 1];
        o[j] = (unsigned)f2bu(lo) | ((unsigned)f2bu(hi) << 16);
    }
    uint4 st4 = make_uint4(o[0], o[1], o[2], o[3]);
    *(uint4*)&out[base] = st4;
}

// ---------------- stride-1 conv: async global_load_lds staging --------------
// LDS is item-linear (global_load_lds writes wave-uniform base + lane*16);
// the bank swizzle is applied on the GLOBAL source address (XOR involution
// grp = sub ^ f(x)), so LDS contents are byte-identical to the old register
// staging and the read side is unchanged. Halo lanes load from a zero page.
template <int CI, int CO_TOTAL, int CO_BLK, int EPI, int ROWS = 4>
__global__ __launch_bounds__(ROWS * 64) void conv_lds(const bf16* __restrict__ in,
                                                      const bf16* __restrict__ wpk,
                                                      const float* __restrict__ bias,
                                                      const void* __restrict__ res,
                                                      void* __restrict__ out,
                                                      const bf16* __restrict__ zpage,
                                                      int in_s0, int out_s0) {
    constexpr int CHUNKS = CI / 32;
    constexpr int MT = CO_BLK / 16;
    constexpr int NG = 64 / ROWS;
    constexpr int NT = ROWS * 64;
    constexpr int HR = ROWS + 2;
    constexpr int IN_ITEMS = HR * 66 * 4;                 // 16B items
    constexpr int IN_PAD = ((IN_ITEMS + 63) / 64) * 64;   // wave-group padded
    constexpr int IN_ITERS = (IN_PAD + NT - 1) / NT;
    constexpr int W_ITEMS = 9 * CO_BLK * 4;               // always %64 == 0
    constexpr int W_ITERS = (W_ITEMS + NT - 1) / NT;

    __shared__ short s_in[IN_PAD * 8];
    __shared__ short s_w[9 * CO_BLK * 32];

    const int tid = threadIdx.x;
    const int lane = tid & 63;
    const int wv = tid >> 6;
    const int quad = lane >> 4;
    const int n16 = lane & 15;

    const int ng = blockIdx.x % NG;
    const int cg = blockIdx.x / NG;
    const int co0 = cg * CO_BLK;
    const int smp = blockIdx.y;
    const int y0 = ng * ROWS;

    const size_t in_base = (size_t)(in_s0 + smp) * 4096 * CI;

    // chunk-invariant staging geometry (source pre-swizzled, -1 => zero page)
    int gin[IN_ITERS];
#pragma unroll
    for (int it = 0; it < IN_ITERS; ++it) {
        int i = it * NT + tid;
        int sub = i & 3;
        int x = (i >> 2) % 66;
        int row = i / 264;
        int y = y0 + row - 1;
        int xg = x - 1;
        bool ok = (i < IN_ITEMS) && (y >= 0) && (y < 64) && (xg >= 0) && (xg < 64);
        int grp = sub ^ (x & 3) ^ ((x >> 2) & 1);
        gin[it] = ok ? ((y * 64 + xg) * CI + grp * 8) : -1;
    }
    int gw[W_ITERS];
#pragma unroll
    for (int it = 0; it < W_ITERS; ++it) {
        int i = it * NT + tid;
        if (i < W_ITEMS) {
            int sub = i & 3;
            int co = (i >> 2) % CO_BLK;
            int tap = i / (CO_BLK * 4);
            int grp = sub ^ (co & 3) ^ ((co >> 2) & 1);
            gw[it] = (tap * CO_TOTAL + co0 + co) * CI + grp * 8;
        } else gw[it] = 0;
    }

    f32x4 acc[MT][4];
#pragma unroll
    for (int mt = 0; mt < MT; ++mt)
#pragma unroll
        for (int j = 0; j < 4; ++j) acc[mt][j] = (f32x4){0.f, 0.f, 0.f, 0.f};

    for (int chunk = 0; chunk < CHUNKS; ++chunk) {
        const int ci0 = chunk * 32;
        __syncthreads();
#pragma unroll
        for (int it = 0; it < IN_ITERS; ++it) {
            int i0 = it * NT + (tid & ~63);
            if (i0 < IN_PAD) {
                const bf16* gp = (gin[it] >= 0) ? (in + in_base + gin[it] + ci0) : zpage;
                gload16(gp, s_in + (size_t)i0 * 8);
            }
        }
#pragma unroll
        for (int it = 0; it < W_ITERS; ++it) {
            int i0 = it * NT + (tid & ~63);
            if (i0 < W_ITEMS) {
                const bf16* gp = wpk + gw[it] + ci0;
                gload16(gp, s_w + (size_t)i0 * 8);
            }
        }
        __syncthreads();

#pragma unroll
        for (int ky = 0; ky < 3; ++ky) {
#pragma unroll
            for (int kx = 0; kx < 3; ++kx) {
                const int tap = ky * 3 + kx;
                bf16x8 bfrag[4];
#pragma unroll
                for (int j = 0; j < 4; ++j) {
                    int x = j * 16 + n16 + kx;
                    int ps = quad ^ (x & 3) ^ ((x >> 2) & 1);
                    bfrag[j] = *(const bf16x8*)&s_in[((wv + ky) * 66 + x) * 32 + ps * 8];
                }
#pragma unroll
                for (int mt = 0; mt < MT; ++mt) {
                    int mrow = mt * 16 + n16;
                    int ps = quad ^ (mrow & 3) ^ ((mrow >> 2) & 1);
                    bf16x8 afrag = *(const bf16x8*)&s_w[(tap * CO_BLK + mrow) * 32 + ps * 8];
#pragma unroll
                    for (int j = 0; j < 4; ++j)
                        acc[mt][j] = __builtin_amdgcn_mfma_f32_16x16x32_bf16(afrag, bfrag[j], acc[mt][j], 0, 0, 0);
                }
            }
        }
    }

    const int osmp = out_s0 + smp;
#pragma unroll
    for (int j = 0; j < 4; ++j) {
        int pos = (y0 + wv) * 64 + j * 16 + n16;
#pragma unroll
        for (int mt = 0; mt < MT; ++mt) {
            int coutb = co0 + mt * 16 + quad * 4;
            float b0 = 0.f, b1 = 0.f, b2 = 0.f, b3 = 0.f;
            if constexpr (EPI != 1) {
                float4 bv = *(const float4*)&bias[coutb];
                b0 = bv.x; b1 = bv.y; b2 = bv.z; b3 = bv.w;
            }
            float v0 = acc[mt][j][0] + b0;
            float v1 = acc[mt][j][1] + b1;
            float v2 = acc[mt][j][2] + b2;
            float v3 = acc[mt][j][3] + b3;
            if constexpr (EPI == 1 || EPI == 2 || EPI == 3) {
                if constexpr (EPI == 2) {
                    const float* xr = (const float*)res + (size_t)osmp * 131072 + (size_t)coutb * 4096 + pos;
                    v0 += xr[0]; v1 += xr[4096]; v2 += xr[8192]; v3 += xr[12288];
                } else if constexpr (EPI == 3) {
                    v0 = gelu_new(v0); v1 = gelu_new(v1); v2 = gelu_new(v2); v3 = gelu_new(v3);
                }
                ushort4 st;
                st.x = f2bu(v0); st.y = f2bu(v1); st.z = f2bu(v2); st.w = f2bu(v3);
                *(ushort4*)&((bf16*)out)[((size_t)osmp * 4096 + pos) * CO_TOTAL + coutb] = st;
            } else {
                ushort4 rv = *(const ushort4*)&((const bf16*)res)[((size_t)osmp * 4096 + pos) * 32 + coutb];
                v0 += su2f(rv.x); v1 += su2f(rv.y); v2 += su2f(rv.z); v3 += su2f(rv.w);
                float* op = (float*)out + (size_t)osmp * 131072 + (size_t)coutb * 4096 + pos;
                op[0] = v0; op[4096] = v1; op[8192] = v2; op[12288] = v3;
            }
        }
    }
}

// ---------------- stride-2 conv (k,q merged: CO_TOTAL=64) ----------------
template <int CI, int CI_BLK, int CO_TOTAL, int CO_BLK, int S, int EPI>
__global__ __launch_bounds__(256) void conv_mfma(const bf16* __restrict__ in,
                                                 const bf16* __restrict__ wpk,
                                                 const float* __restrict__ bias,
                                                 const void* __restrict__ res,
                                                 void* __restrict__ out,
                                                 int in_s0, int out_s0) {
    constexpr int WO = 64 / S;
    constexpr int HO = 64 / S;
    constexpr int NG = (HO * WO) / 256;
    constexpr int TPR = WO / 16;
    constexpr int MT = CO_BLK / 16;
    constexpr int PHASES = CI / CI_BLK;
    constexpr int KC = CI_BLK / 32;
    constexpr int PAD = CI_BLK + 8;

    __shared__ short s_w[9 * CO_BLK * PAD];

    const int tid = threadIdx.x;
    const int lane = tid & 63;
    const int wv = tid >> 6;
    const int quad = lane >> 4;
    const int n16 = lane & 15;

    const int ng = blockIdx.x % NG;
    const int cg = blockIdx.x / NG;
    const int co0 = cg * CO_BLK;
    const int smp = blockIdx.y;

    f32x4 acc[MT][4];
#pragma unroll
    for (int mt = 0; mt < MT; ++mt)
#pragma unroll
        for (int j = 0; j < 4; ++j) acc[mt][j] = (f32x4){0.f, 0.f, 0.f, 0.f};

    const size_t in_base = (size_t)(in_s0 + smp) * 4096 * CI;

    for (int phase = 0; phase < PHASES; ++phase) {
        const int ci0 = phase * CI_BLK;
        __syncthreads();
        for (int idx = tid; idx < 9 * CO_BLK * CI_BLK / 4; idx += 256) {
            int e = idx * 4;
            int tap = e / (CO_BLK * CI_BLK);
            int rem = e - tap * (CO_BLK * CI_BLK);
            int col = rem / CI_BLK;
            int k = rem - col * CI_BLK;
            const ushort4 src = *(const ushort4*)&wpk[((size_t)tap * CO_TOTAL + co0 + col) * CI + ci0 + k];
            *(ushort4*)&s_w[(tap * CO_BLK + col) * PAD + k] = src;
        }
        __syncthreads();

#pragma unroll
        for (int ky = 0; ky < 3; ++ky) {
#pragma unroll
            for (int kx = 0; kx < 3; ++kx) {
                const int tap = ky * 3 + kx;
                bf16x8 bfrag[KC][4];
#pragma unroll
                for (int kc = 0; kc < KC; ++kc) {
#pragma unroll
                    for (int j = 0; j < 4; ++j) {
                        int tile = ng * 16 + wv * 4 + j;
                        int yo = tile / TPR;
                        int xo = (tile % TPR) * 16;
                        int xi = (xo + n16) * S + kx - 1;
                        int yi = yo * S + ky - 1;
                        bool valid = (xi >= 0) && (xi < 64) && (yi >= 0) && (yi < 64);
                        uint4 u;
                        if (valid)
                            u = *(const uint4*)&in[in_base + ((size_t)yi * 64 + xi) * CI + ci0 + kc * 32 + quad * 8];
                        else
                            u = make_uint4(0u, 0u, 0u, 0u);
                        __builtin_memcpy(&bfrag[kc][j], &u, 16);
                    }
                }
#pragma unroll
                for (int kc = 0; kc < KC; ++kc) {
#pragma unroll
                    for (int mt = 0; mt < MT; ++mt) {
                        bf16x8 afrag = *(const bf16x8*)&s_w[(tap * CO_BLK + mt * 16 + n16) * PAD + kc * 32 + quad * 8];
#pragma unroll
                        for (int j = 0; j < 4; ++j)
                            acc[mt][j] = __builtin_amdgcn_mfma_f32_16x16x32_bf16(afrag, bfrag[kc][j], acc[mt][j], 0, 0, 0);
                    }
                }
            }
        }
    }

    const int osmp = out_s0 + smp;
#pragma unroll
    for (int j = 0; j < 4; ++j) {
        int tile = ng * 16 + wv * 4 + j;
        int yo = tile / TPR;
        int xo = (tile % TPR) * 16;
        int pos = yo * WO + xo + n16;
#pragma unroll
        for (int mt = 0; mt < MT; ++mt) {
            int coutb = co0 + mt * 16 + quad * 4;
            ushort4 st;
            st.x = f2bu(acc[mt][j][0]); st.y = f2bu(acc[mt][j][1]);
            st.z = f2bu(acc[mt][j][2]); st.w = f2bu(acc[mt][j][3]);
            *(ushort4*)&((bf16*)out)[((size_t)osmp * HO * WO + pos) * CO_TOTAL + coutb] = st;
        }
    }
}

// ---------------- attention scores + softmax : fused MFMA ----------------
// KQ merged layout: [bt][1024 p][64 c]; K = c 0..31, Q = c 32..63.
__global__ __launch_bounds__(256) void attn_scores_mfma(const bf16* __restrict__ KQ,
                                                        bf16* __restrict__ att) {
    __shared__ float red[4][32][33];
    __shared__ float sc[32][33];
    const int tid = threadIdx.x;
    const int lane = tid & 63;
    const int wv = tid >> 6;
    const int quad = lane >> 4;
    const int n16 = lane & 15;
    const int h = blockIdx.x & 7;
    const int b = blockIdx.x >> 3;
    const size_t base = (size_t)b * 32 * 65536 + (size_t)h * 4;

    f32x4 acc[2][2];
#pragma unroll
    for (int mt = 0; mt < 2; ++mt)
#pragma unroll
        for (int nt = 0; nt < 2; ++nt) acc[mt][nt] = (f32x4){0.f, 0.f, 0.f, 0.f};

    for (int kc = 0; kc < 32; ++kc) {
        const int p0 = wv * 256 + kc * 8 + quad * 2;
        bf16x8 afrag[2], bfrag[2];
#pragma unroll
        for (int mt = 0; mt < 2; ++mt) {
            const bf16* qp = &KQ[base + 32 + (size_t)(mt * 16 + n16) * 65536 + (size_t)p0 * 64];
            uint2 lo = *(const uint2*)qp;
            uint2 hi = *(const uint2*)(qp + 64);
            uint4 u = make_uint4(lo.x, lo.y, hi.x, hi.y);
            __builtin_memcpy(&afrag[mt], &u, 16);
        }
#pragma unroll
        for (int nt = 0; nt < 2; ++nt) {
            const bf16* kp = &KQ[base + (size_t)(nt * 16 + n16) * 65536 + (size_t)p0 * 64];
            uint2 lo = *(const uint2*)kp;
            uint2 hi = *(const uint2*)(kp + 64);
            uint4 u = make_uint4(lo.x, lo.y, hi.x, hi.y);
            __builtin_memcpy(&bfrag[nt], &u, 16);
        }
#pragma unroll
        for (int mt = 0; mt < 2; ++mt)
#pragma unroll
            for (int nt = 0; nt < 2; ++nt)
                acc[mt][nt] = __builtin_amdgcn_mfma_f32_16x16x32_bf16(afrag[mt], bfrag[nt], acc[mt][nt], 0, 0, 0);
    }
#pragma unroll
    for (int mt = 0; mt < 2; ++mt)
#pragma unroll
        for (int nt = 0; nt < 2; ++nt)
#pragma unroll
            for (int r = 0; r < 4; ++r)
                red[wv][mt * 16 + quad * 4 + r][nt * 16 + n16] = acc[mt][nt][r];
    __syncthreads();
    for (int i = tid; i < 1024; i += 256) {
        int t = i >> 5, s = i & 31;
        sc[t][s] = (red[0][t][s] + red[1][t][s] + red[2][t][s] + red[3][t][s]) * (1.0f / 64.0f);
    }
    __syncthreads();
    if (tid < 32) {
        float mx = -1e30f;
        for (int s2 = 0; s2 < 32; ++s2) mx = fmaxf(mx, sc[tid][s2]);
        float sum = 0.f;
        for (int s2 = 0; s2 < 32; ++s2) sum += expf(sc[tid][s2] - mx);
        float inv = 1.f / sum;
        bf16* arow = &att[((size_t)blockIdx.x * 32 + tid) * 32];
        for (int s2 = 0; s2 < 32; ++s2) arow[s2] = f2b(expf(sc[tid][s2] - mx) * inv);
    }
}

// ---------------- y = att @ v : MFMA with fused in-LDS V transpose ----------
__global__ __launch_bounds__(256) void attn_apply_mfma(const bf16* __restrict__ att,
                                                       const bf16* __restrict__ V,
                                                       bf16* __restrict__ Y) {
    __shared__ short vlds[512 * 40];
    __shared__ short ylds[32 * 512];
    const int tid = threadIdx.x;
    const int lane = tid & 63;
    const int wv = tid >> 6;
    const int quad = lane >> 4;
    const int n16 = lane & 15;
    const int pb = blockIdx.x;
    const int b = blockIdx.y;

    for (int l = 0; l < 8; ++l) {
        int u = l * 256 + tid;
        int s = u >> 6;
        int col8 = (u & 63) * 8;
        uint4 v = *(const uint4*)&V[(((size_t)(b * 32 + s) * 4096 + pb * 16) * 32) + col8];
        unsigned short us[8];
        __builtin_memcpy(us, &v, 16);
#pragma unroll
        for (int j = 0; j < 8; ++j) {
            int idx = col8 + j;
            int p = idx >> 5, c = idx & 31;
            int row = ((c >> 2) * 16 + p) * 4 + (c & 3);
            vlds[row * 40 + s] = (short)us[j];
        }
    }
    __syncthreads();

    const int e = wv * 16 + n16;
    const int p = e >> 2, cl = e & 3;
    for (int h = 0; h < 8; ++h) {
        bf16x8 bfrag = *(const bf16x8*)&vlds[(h * 64 + e) * 40 + quad * 8];
        const int c = h * 4 + cl;
#pragma unroll
        for (int mt = 0; mt < 2; ++mt) {
            bf16x8 afrag = *(const bf16x8*)&att[((size_t)(b * 8 + h) * 32 + mt * 16 + n16) * 32 + quad * 8];
            f32x4 d = __builtin_amdgcn_mfma_f32_16x16x32_bf16(afrag, bfrag,
                                                              (f32x4){0.f, 0.f, 0.f, 0.f}, 0, 0, 0);
#pragma unroll
            for (int r = 0; r < 4; ++r) {
                int t = mt * 16 + quad * 4 + r;
                ylds[t * 512 + p * 32 + c] = (short)f2bu(d[r]);
            }
        }
    }
    __syncthreads();

    for (int l = 0; l < 8; ++l) {
        int u = l * 256 + tid;
        int t = u >> 6;
        int col8 = (u & 63) * 8;
        *(uint4*)&Y[(((size_t)(b * 32 + t) * 4096 + pb * 16) * 32) + col8] =
            *(const uint4*)&ylds[t * 512 + col8];
    }
}

extern "C" void kernel_launch(void* const* d_in, const int* in_sizes, int n_in,
                              void* d_out, int out_size, void* d_ws, size_t ws_size,
                              hipStream_t stream) {
    const float* x   = (const float*)d_in[0];
    const float* n1g = (const float*)d_in[1];
    const float* n1b = (const float*)d_in[2];
    const float* n2g = (const float*)d_in[3];
    const float* n2b = (const float*)d_in[4];
    const float* Wk  = (const float*)d_in[5];
    const float* Wq  = (const float*)d_in[6];
    const float* Wv  = (const float*)d_in[7];
    const float* Wo  = (const float*)d_in[8];
    const float* bo  = (const float*)d_in[9];
    const float* Wm1 = (const float*)d_in[10];
    const float* bm1 = (const float*)d_in[11];
    const float* Wm2 = (const float*)d_in[12];
    const float* bm2 = (const float*)d_in[13];

    char* ws = (char*)d_ws;
    const size_t A_OFF = 0;
    const size_t B_OFF = 33554432;
    const size_t D_OFF = 67108864;
    const size_t E_OFF = 67239936;
    const size_t F_OFF = 67461120;
    const size_t C_OFF = 68519936;

    bf16*  xn   = (bf16*)(ws + A_OFF);
    bf16*  Yb   = (bf16*)(ws + A_OFF);
    bf16*  xn2  = (bf16*)(ws + A_OFF);
    bf16*  Vb   = (bf16*)(ws + B_OFF);
    bf16*  X1   = (bf16*)(ws + B_OFF);
    bf16*  attbf = (bf16*)(ws + D_OFF);
    bf16*  wpk_kq = (bf16*)(ws + E_OFF);            // 9*64*32*2 = 36864 B
    bf16*  wpk_v  = (bf16*)(ws + E_OFF + 36864);
    bf16*  wpk_o  = (bf16*)(ws + E_OFF + 55296);
    bf16*  wpk_m1 = (bf16*)(ws + E_OFF + 73728);
    bf16*  wpk_m2 = (bf16*)(ws + E_OFF + 147456);
    float* g2t  = (float*)(ws + F_OFF);
    float* b2t  = (float*)(ws + F_OFF + 524288);
    float2* spart = (float2*)(ws + F_OFF + 1048576);
    float2* stats = (float2*)(ws + F_OFF + 1056768);
    bf16*  zpg  = (bf16*)(ws + F_OFF + 1057792);    // 256 B zero page
    bf16*  KQb  = (bf16*)(ws + C_OFF);              // [128][1024][64] bf16 = 16 MB
    bf16*  Hb   = (bf16*)(ws + C_OFF);

    const size_t HB_PER_SAMPLE = 1048576;
    int chunk = 128;
    if (ws_size < C_OFF + 128 * HB_PER_SAMPLE) {
        size_t avail = (ws_size > C_OFF) ? (ws_size - C_OFF) : HB_PER_SAMPLE;
        chunk = (int)(avail / HB_PER_SAMPLE);
        if (chunk < 1) chunk = 1;
        if (chunk > 128) chunk = 128;
    }

    // 0. pack weights (k,q merged); transpose LN2 g/b; zero page
    pack_w<<<36, 256, 0, stream>>>(Wk, wpk_kq, 32, 32, 64, 0);
    pack_w<<<36, 256, 0, stream>>>(Wq, wpk_kq, 32, 32, 64, 32);
    pack_w<<<36, 256, 0, stream>>>(Wv, wpk_v, 32, 32, 32, 0);
    pack_w<<<36, 256, 0, stream>>>(Wo, wpk_o, 32, 32, 32, 0);
    pack_w<<<144, 256, 0, stream>>>(Wm1, wpk_m1, 128, 32, 128, 0);
    pack_w<<<144, 256, 0, stream>>>(Wm2, wpk_m2, 32, 128, 32, 0);
    gtrans_k<<<1024, 256, 0, stream>>>(n2g, n2b, g2t, b2t);
    zero_page<<<1, 64, 0, stream>>>((float*)zpg);

    // 1. LN1: x (NCHW f32) -> xn (NHWC bf16)
    ln_part<float><<<dim3(8, 128), 256, 0, stream>>>(x, spart);
    ln_fin<<<1, 128, 0, stream>>>(spart, stats);
    ln1_norm_t<<<dim3(32, 128), 256, 0, stream>>>(x, n1g, n1b, stats, xn);
    // 2-3. k+q merged (stride 2, CO=64), v (stride 1 LDS, 4-row)
    conv_mfma<32, 32, 64, 64, 2, 1><<<dim3(4, 128), 256, 0, stream>>>(xn, wpk_kq, nullptr, nullptr, KQb, 0, 0);
    conv_lds<32, 32, 32, 1, 4><<<dim3(16, 128), 256, 0, stream>>>(xn, wpk_v, nullptr, nullptr, Vb, zpg, 0, 0);
    // 5. attention scores + softmax (fused MFMA, merged KQ input)
    attn_scores_mfma<<<32, 256, 0, stream>>>(KQb, attbf);
    // 6. y = att @ v
    attn_apply_mfma<<<dim3(256, 4), 256, 0, stream>>>(attbf, Vb, Yb);
    // 7. Wo conv + bias + residual x -> X1 (4-row)
    conv_lds<32, 32, 32, 2, 4><<<dim3(16, 128), 256, 0, stream>>>(Yb, wpk_o, bo, x, X1, zpg, 0, 0);
    // 8. LN2
    ln_part<bf16><<<dim3(8, 128), 256, 0, stream>>>(X1, spart);
    ln_fin<<<1, 128, 0, stream>>>(spart, stats);
    ln2_norm<<<dim3(64, 128), 256, 0, stream>>>(X1, g2t, b2t, stats, xn2);
    // 9-10. mixer: 8-row blocks + async global_load_lds staging
    for (int s0 = 0; s0 < 128; s0 += chunk) {
        int n = (128 - s0 < chunk) ? (128 - s0) : chunk;
        conv_lds<32, 128, 64, 3, 8><<<dim3(16, n), 512, 0, stream>>>(xn2, wpk_m1, bm1, nullptr, Hb, zpg, s0, 0);
        conv_lds<128, 32, 32, 4, 8><<<dim3(8, n), 512, 0, stream>>>(Hb, wpk_m2, bm2, X1, (float*)d_out, zpg, 0, s0);
    }
}